// Round 12
// baseline (437.174 us; speedup 1.0000x reference)
//
#include <hip/hip_runtime.h>
#include <hip/hip_bf16.h>
#include <cstdint>

#define HID 64
#define NPG 100

// coarse buckets for CSR build: 1024 dsts per bucket
#define CSHIFT 10
#define CMASK ((1 << CSHIFT) - 1)
#define CAP 56          // LDS slots per bin per tile (λ≈42, spill ~1%)
#define TILE 8192       // edges per phase-1 block
#define SLOT 32768      // staging ints per bucket (mean ~16.6k, 2x slack)

typedef short bf16x8 __attribute__((ext_vector_type(8)));
typedef float f32x4 __attribute__((ext_vector_type(4)));
typedef float f32x2 __attribute__((ext_vector_type(2)));

__device__ __forceinline__ unsigned short bf16_rn(float f) {
    union { float f; unsigned u; } c; c.f = f;
    unsigned r = c.u + 0x7fffu + ((c.u >> 16) & 1u);
    return (unsigned short)(r >> 16);
}
__device__ __forceinline__ float bf16_f(unsigned short h) {
    union { unsigned u; float f; } c; c.u = ((unsigned)h) << 16;
    return c.f;
}
__device__ __forceinline__ float f_lo(unsigned u) {
    union { unsigned u; float f; } c; c.u = u << 16;
    return c.f;
}
__device__ __forceinline__ float f_hi(unsigned u) {
    union { unsigned u; float f; } c; c.u = u & 0xffff0000u;
    return c.f;
}
__device__ __forceinline__ unsigned pack4_fp8(float a, float b, float c, float d) {
    int r = __builtin_amdgcn_cvt_pk_fp8_f32(a, b, 0, false);
    r = __builtin_amdgcn_cvt_pk_fp8_f32(c, d, r, true);
    return (unsigned)r;
}

// decoder chain-graph degree
__device__ __forceinline__ float dinvdec(int p) {
    int d = (p >= 1) + (p >= 2) + (p <= NPG - 2) + (p <= NPG - 3);
    return rsqrtf((float)(d + 1));
}

// ---------------- CSR build (LDS-binned, no cross-XCD line sharing) ----------------

__global__ void zero_int_kernel(int* __restrict__ p, int n) {
    int i = blockIdx.x * 256 + threadIdx.x;
    if (i < n) p[i] = 0;
}

__global__ __launch_bounds__(256) void bin1_kernel(const int* __restrict__ src,
                                                   const int* __restrict__ dst,
                                                   int* __restrict__ gcur,
                                                   int* __restrict__ stage,
                                                   int E, int nbin) {
    __shared__ int bins[256][CAP];
    __shared__ int bcnt[256];
    const int tid = threadIdx.x;
    bcnt[tid] = 0;
    __syncthreads();

    const int e0 = blockIdx.x * TILE;
    const int cnt = min(TILE, E - e0);
    for (int i = tid; i < cnt; i += 256) {
        int s = src[e0 + i], d = dst[e0 + i];
        int b = d >> CSHIFT;
        int v = (s << CSHIFT) | (d & CMASK);
        int pos = atomicAdd(&bcnt[b], 1);
        if (pos < CAP) {
            bins[b][pos] = v;
        } else {  // rare spill: private 4-slot chunk, -1 pads
            int g = atomicAdd(&gcur[b * 16], 4);
            int* sp = stage + (size_t)b * SLOT + g;
            sp[0] = v; sp[1] = -1; sp[2] = -1; sp[3] = -1;
        }
    }
    __syncthreads();

    if (tid < nbin) {
        int c = min(bcnt[tid], CAP);
        int r = (c + 3) & ~3;
        if (r > 0) {
            int base = atomicAdd(&gcur[tid * 16], r);
            int* dstp = stage + (size_t)tid * SLOT + base;
            for (int j = 0; j < r; j += 4) {
                int4 v;
                v.x = (j + 0 < c) ? bins[tid][j + 0] : -1;
                v.y = (j + 1 < c) ? bins[tid][j + 1] : -1;
                v.z = (j + 2 < c) ? bins[tid][j + 2] : -1;
                v.w = (j + 3 < c) ? bins[tid][j + 3] : -1;
                *(int4*)(dstp + j) = v;
            }
        }
    }
}

__global__ __launch_bounds__(256) void bin_count_kernel(const int* __restrict__ gcur,
                                                        const int* __restrict__ stage,
                                                        int* __restrict__ cntg,
                                                        float* __restrict__ dinvg, int N) {
    __shared__ int lc[1 << CSHIFT];
    const int b = blockIdx.x;
    for (int j = threadIdx.x; j < (1 << CSHIFT); j += 256) lc[j] = 0;
    __syncthreads();
    const int len = gcur[b * 16];
    const int* sp = stage + (size_t)b * SLOT;
    for (int i = threadIdx.x; i < len; i += 256) {
        int v = sp[i];
        if (v >= 0) atomicAdd(&lc[v & CMASK], 1);
    }
    __syncthreads();
    const int d0 = b << CSHIFT;
    for (int j = threadIdx.x; j < (1 << CSHIFT); j += 256) {
        int d = d0 + j;
        if (d < N) {
            int c = lc[j];
            cntg[d] = c;
            dinvg[d] = rsqrtf((float)c + 1.0f);
        }
    }
}

__global__ __launch_bounds__(256) void scan1_kernel(const int* __restrict__ cnt,
                                                    int* __restrict__ row_ptr,
                                                    int* __restrict__ partials, int N) {
    __shared__ int sd[256];
    int tid = threadIdx.x;
    int base = blockIdx.x * 2048 + tid * 8;
    int v[8];
    int s = 0;
#pragma unroll
    for (int j = 0; j < 8; j++) {
        int i = base + j;
        int t = (i < N) ? cnt[i] : 0;
        v[j] = t; s += t;
    }
    sd[tid] = s;
    __syncthreads();
    for (int off = 1; off < 256; off <<= 1) {
        int t = (tid >= off) ? sd[tid - off] : 0;
        __syncthreads();
        sd[tid] += t;
        __syncthreads();
    }
    int run = sd[tid] - s;  // exclusive within block
#pragma unroll
    for (int j = 0; j < 8; j++) {
        int i = base + j;
        if (i < N) row_ptr[i] = run;
        run += v[j];
    }
    if (tid == 0) partials[blockIdx.x] = sd[255];
}

__global__ void scan2_kernel(int* __restrict__ partials, int nb) {
    __shared__ int sd[128];
    int tid = threadIdx.x;
    int v = (tid < nb) ? partials[tid] : 0;
    sd[tid] = v;
    __syncthreads();
    for (int off = 1; off < 128; off <<= 1) {
        int t = (tid >= off) ? sd[tid - off] : 0;
        __syncthreads();
        sd[tid] += t;
        __syncthreads();
    }
    if (tid < nb) partials[tid] = sd[tid] - v;
}

__global__ void scan3_kernel(int* __restrict__ row_ptr, const int* __restrict__ partials,
                             int N, int E) {
    int base = blockIdx.x * 2048 + threadIdx.x * 8;
    int add = partials[blockIdx.x];
#pragma unroll
    for (int j = 0; j < 8; j++) {
        int i = base + j;
        if (i < N) row_ptr[i] += add;
    }
    if (blockIdx.x == 0 && threadIdx.x == 0) row_ptr[N] = E;
}

__global__ __launch_bounds__(256) void bin_fill_kernel(const int* __restrict__ gcur,
                                                       const int* __restrict__ stage,
                                                       const int* __restrict__ row_ptr,
                                                       int* __restrict__ csr_src, int N) {
    __shared__ int cur[1 << CSHIFT];
    __shared__ int rp[1 << CSHIFT];
    const int b = blockIdx.x;
    const int d0 = b << CSHIFT;
    for (int j = threadIdx.x; j < (1 << CSHIFT); j += 256) {
        cur[j] = 0;
        int d = d0 + j;
        rp[j] = (d < N) ? row_ptr[d] : 0;
    }
    __syncthreads();
    const int len = gcur[b * 16];
    const int* sp = stage + (size_t)b * SLOT;
    for (int i = threadIdx.x; i < len; i += 256) {
        int v = sp[i];
        if (v >= 0) {
            int dl = v & CMASK;
            int pos = rp[dl] + atomicAdd(&cur[dl], 1);
            csr_src[pos] = v >> CSHIFT;
        }
    }
}

// ---------------- MFMA GEMM ----------------
// AMODE: 0 = fp32 A direct; 1 = packed bf16 A direct;
//        2 = closed-form decoder z1 (A = tbuf [NG][64], apre = b1);
//        3 = stencil over fp32 g; 4 = stencil over bf16 g;
//        5 = packed fp8 e4m3 A (decode in-reg).
// WP: 1 = plain bf16 W (1 MFMA), 2 = hi/lo split W+A (3 MFMA, fp32-grade).
// OMODE: 0 = fp32 out, 1 = packed bf16 out, 2 = packed fp8 e4m3 out.
template <int K, int N, int SCALE_MODE, bool BIAS, int AMODE, int WP, int OMODE>
__global__ __launch_bounds__(256, 2) void mfma_gemm(const float* __restrict__ A,
                                                    const float* __restrict__ W,
                                                    const float* __restrict__ bias,
                                                    const float* __restrict__ rowscale,
                                                    const float* __restrict__ apre,
                                                    float* __restrict__ out, int M) {
    constexpr int KP = K + 8;
    constexpr int NT = N / 16;
    constexpr int KS = K / 32;
    __shared__ unsigned short Wt[WP][N][KP];
    const int tid = threadIdx.x;

    for (int idx = tid; idx < K * N; idx += 256) {
        float w = W[idx];
        int k = idx / N, n = idx % N;  // N is pow2
        unsigned short h = bf16_rn(w);
        Wt[0][n][k] = h;
        if (WP == 2) Wt[1][n][k] = bf16_rn(w - bf16_f(h));
    }
    __syncthreads();

    const int lane = tid & 63;
    const int l15 = lane & 15;
    const int lg = lane >> 4;  // 0..3
    const int nstrips = M / 16;
    const int wglobal = blockIdx.x * 4 + (tid >> 6);
    const int wtotal = gridDim.x * 4;

    float curf[AMODE != 1 ? KS * 8 : 1], nxtf[AMODE != 1 ? KS * 8 : 1];
    uint4 curv[AMODE == 1 ? KS : 1], nxtv[AMODE == 1 ? KS : 1];

    // pre-bias (A-construction bias) for modes 2/3/4 — constant across strips
    float preb[(AMODE >= 2 && AMODE <= 4) ? KS * 8 : 1];
    if (AMODE >= 2 && AMODE <= 4) {
#pragma unroll
        for (int ks = 0; ks < KS; ks++)
#pragma unroll
            for (int j = 0; j < 8; j++) preb[ks * 8 + j] = apre[ks * 32 + lg * 8 + j];
    }

    auto loadA_f = [&](int s, float* dstv) {
        const float* arow = A + (size_t)(s * 16 + l15) * K + lg * 8;
#pragma unroll
        for (int ks = 0; ks < KS; ks++) {
            float4 a = *(const float4*)(arow + ks * 32);
            float4 b = *(const float4*)(arow + ks * 32 + 4);
            dstv[ks * 8 + 0] = a.x; dstv[ks * 8 + 1] = a.y;
            dstv[ks * 8 + 2] = a.z; dstv[ks * 8 + 3] = a.w;
            dstv[ks * 8 + 4] = b.x; dstv[ks * 8 + 5] = b.y;
            dstv[ks * 8 + 6] = b.z; dstv[ks * 8 + 7] = b.w;
        }
    };
    auto loadA_h = [&](int s, uint4* dstv) {
        const unsigned short* arow = (const unsigned short*)A + (size_t)(s * 16 + l15) * K + lg * 8;
#pragma unroll
        for (int ks = 0; ks < KS; ks++)
            dstv[ks] = *(const uint4*)(arow + ks * 32);
    };
    // mode 5: packed fp8 A -> decode to fp32
    auto loadA_f8 = [&](int s, float* dstv) {
        const unsigned char* arow = (const unsigned char*)A + (size_t)(s * 16 + l15) * K + lg * 8;
#pragma unroll
        for (int ks = 0; ks < KS; ks++) {
            uint2 v = *(const uint2*)(arow + ks * 32);
            f32x2 a0 = __builtin_amdgcn_cvt_pk_f32_fp8((int)v.x, false);
            f32x2 a1 = __builtin_amdgcn_cvt_pk_f32_fp8((int)v.x, true);
            f32x2 a2 = __builtin_amdgcn_cvt_pk_f32_fp8((int)v.y, false);
            f32x2 a3 = __builtin_amdgcn_cvt_pk_f32_fp8((int)v.y, true);
            dstv[ks * 8 + 0] = a0[0]; dstv[ks * 8 + 1] = a0[1];
            dstv[ks * 8 + 2] = a1[0]; dstv[ks * 8 + 3] = a1[1];
            dstv[ks * 8 + 4] = a2[0]; dstv[ks * 8 + 5] = a2[1];
            dstv[ks * 8 + 6] = a3[0]; dstv[ks * 8 + 7] = a3[1];
        }
    };
    // mode 2: z1 closed form from tbuf
    auto loadA_z1 = [&](int s, float* dstv) {
        int grow = s * 16 + l15;
        int gph = grow / NPG;
        int p = grow - gph * NPG;
        float dp = dinvdec(p);
        float qs = dp;
        if (p >= 1) qs += dinvdec(p - 1);
        if (p >= 2) qs += dinvdec(p - 2);
        if (p <= NPG - 2) qs += dinvdec(p + 1);
        if (p <= NPG - 3) qs += dinvdec(p + 2);
        float sc = dp * qs;
#pragma unroll
        for (int ks = 0; ks < KS; ks++) {
            const float* tr = A + gph * HID + ks * 32 + lg * 8;
            float4 a = *(const float4*)tr;
            float4 b = *(const float4*)(tr + 4);
            float av[8] = {a.x, a.y, a.z, a.w, b.x, b.y, b.z, b.w};
#pragma unroll
            for (int j = 0; j < 8; j++)
                dstv[ks * 8 + j] = fmaxf(sc * av[j] + preb[ks * 8 + j], 0.f);
        }
    };
    // modes 3/4: 5-point stencil over g (fp32 or bf16) + bias + relu
    auto loadA_st = [&](int s, float* dstv) {
        int grow = s * 16 + l15;
        int gph = grow / NPG;
        int p = grow - gph * NPG;
        float dd = dinvdec(p);
#pragma unroll
        for (int ks = 0; ks < KS; ks++) {
            float acc8[8] = {0.f, 0.f, 0.f, 0.f, 0.f, 0.f, 0.f, 0.f};
            const int cb = ks * 32 + lg * 8;
            if (AMODE == 3) {
                const float* base = A + (size_t)grow * K + cb;
                auto addr = [&](const float* rp) {
                    float4 a = *(const float4*)rp;
                    float4 b = *(const float4*)(rp + 4);
                    acc8[0] += a.x; acc8[1] += a.y; acc8[2] += a.z; acc8[3] += a.w;
                    acc8[4] += b.x; acc8[5] += b.y; acc8[6] += b.z; acc8[7] += b.w;
                };
                addr(base);
                if (p >= 1) addr(base - K);
                if (p >= 2) addr(base - 2 * K);
                if (p <= NPG - 2) addr(base + K);
                if (p <= NPG - 3) addr(base + 2 * K);
            } else {
                const unsigned short* base = (const unsigned short*)A + (size_t)grow * K + cb;
                auto addr = [&](const unsigned short* rp) {
                    uint4 v = *(const uint4*)rp;
                    acc8[0] += f_lo(v.x); acc8[1] += f_hi(v.x);
                    acc8[2] += f_lo(v.y); acc8[3] += f_hi(v.y);
                    acc8[4] += f_lo(v.z); acc8[5] += f_hi(v.z);
                    acc8[6] += f_lo(v.w); acc8[7] += f_hi(v.w);
                };
                addr(base);
                if (p >= 1) addr(base - K);
                if (p >= 2) addr(base - 2 * K);
                if (p <= NPG - 2) addr(base + K);
                if (p <= NPG - 3) addr(base + 2 * K);
            }
#pragma unroll
            for (int j = 0; j < 8; j++)
                dstv[ks * 8 + j] = fmaxf(dd * acc8[j] + preb[ks * 8 + j], 0.f);
        }
    };

    auto loadA = [&](int s) {
        if (AMODE == 0) loadA_f(s, nxtf);
        else if (AMODE == 1) loadA_h(s, nxtv);
        else if (AMODE == 2) loadA_z1(s, nxtf);
        else if (AMODE == 5) loadA_f8(s, nxtf);
        else loadA_st(s, nxtf);
    };

    int s = wglobal;
    if (s < nstrips) {
        loadA(s);
        if (AMODE == 1) { for (int i = 0; i < KS; i++) curv[i] = nxtv[i]; }
        else            { for (int i = 0; i < KS * 8; i++) curf[i] = nxtf[i]; }
    }
    for (; s < nstrips; s += wtotal) {
        int sn = s + wtotal;
        if (sn < nstrips) loadA(sn);

        f32x4 acc[NT];
#pragma unroll
        for (int t = 0; t < NT; t++) acc[t] = f32x4{0.f, 0.f, 0.f, 0.f};

#pragma unroll
        for (int ks = 0; ks < KS; ks++) {
            bf16x8 ah, al;
            if (AMODE == 1) {
                ah = *(bf16x8*)&curv[ks];
            } else {
#pragma unroll
                for (int j = 0; j < 8; j++) {
                    float v = curf[ks * 8 + j];
                    unsigned short h = bf16_rn(v);
                    ah[j] = (short)h;
                    if (WP == 2) al[j] = (short)bf16_rn(v - bf16_f(h));
                }
            }
            const int k0 = ks * 32 + lg * 8;
#pragma unroll
            for (int t = 0; t < NT; t++) {
                int n = t * 16 + l15;
                bf16x8 bh = *(const bf16x8*)&Wt[0][n][k0];
                acc[t] = __builtin_amdgcn_mfma_f32_16x16x32_bf16(ah, bh, acc[t], 0, 0, 0);
                if (WP == 2) {
                    bf16x8 bl = *(const bf16x8*)&Wt[1][n][k0];
                    acc[t] = __builtin_amdgcn_mfma_f32_16x16x32_bf16(ah, bl, acc[t], 0, 0, 0);
                    acc[t] = __builtin_amdgcn_mfma_f32_16x16x32_bf16(al, bh, acc[t], 0, 0, 0);
                }
            }
        }

#pragma unroll
        for (int r = 0; r < 4; r++) {
            int row = s * 16 + lg * 4 + r;
            float scale = 1.0f;
            if (SCALE_MODE == 1) scale = rowscale[row];
            if (SCALE_MODE == 2) scale = dinvdec(row % NPG);
#pragma unroll
            for (int t = 0; t < NT; t++) {
                float o = acc[t][r] * scale;
                if (BIAS) o += bias[t * 16 + l15];
                if (OMODE == 2) {
                    int p = __builtin_amdgcn_cvt_pk_fp8_f32(o, 0.0f, 0, false);
                    ((unsigned char*)out)[(size_t)row * N + t * 16 + l15] = (unsigned char)(p & 0xff);
                } else if (OMODE == 1) {
                    ((unsigned short*)out)[(size_t)row * N + t * 16 + l15] = bf16_rn(o);
                } else {
                    out[(size_t)row * N + t * 16 + l15] = o;
                }
            }
        }
        if (AMODE == 1) {
#pragma unroll
            for (int i = 0; i < KS; i++) curv[i] = nxtv[i];
        } else {
#pragma unroll
            for (int i = 0; i < KS * 8; i++) curf[i] = nxtf[i];
        }
    }
}

// ---------------- encoder aggregation (gather over CSR, fp8 rows -> fp8 h) ----------------
// Barrier-free; 4 lanes/row (uint4 = 16 fp8); 16-deep index+gather pipeline.
// out: h = relu?(dinv*sum + bias) packed fp8.
__global__ __launch_bounds__(256) void agg_f8_kernel(const unsigned int* __restrict__ g,
                                                     const int* __restrict__ row_ptr,
                                                     const int* __restrict__ csr_src,
                                                     const float* __restrict__ dinv,
                                                     const float* __restrict__ bias,
                                                     unsigned int* __restrict__ out,
                                                     int N, int do_relu) {
    const int tid = threadIdx.x;
    const int sub = tid >> 2;        // 0..63: row within block
    const int lg = tid & 3;          // 16B group (16 fp8 values)
    const int row = blockIdx.x * 64 + sub;
    if (row >= N) return;

    const uint4* g4 = (const uint4*)g;
    float acc[16] = {};

#define D4(u, i0) do { \
    f32x2 lo = __builtin_amdgcn_cvt_pk_f32_fp8((int)(u), false); \
    f32x2 hi = __builtin_amdgcn_cvt_pk_f32_fp8((int)(u), true); \
    acc[i0 + 0] += lo[0]; acc[i0 + 1] += lo[1]; \
    acc[i0 + 2] += hi[0]; acc[i0 + 3] += hi[1]; } while (0)
#define ACCV(vv) do { D4(vv.x, 0); D4(vv.y, 4); D4(vv.z, 8); D4(vv.w, 12); } while (0)

    {   // self term
        uint4 v = g4[(size_t)row * 4 + lg];
        ACCV(v);
    }

    const int s = row_ptr[row];
    const int e = row_ptr[row + 1];
    int j = s;

    for (; j + 16 <= e; j += 16) {
        int idx[16];
#pragma unroll
        for (int t = 0; t < 16; t++) idx[t] = csr_src[j + t];
        uint4 v[16];
#pragma unroll
        for (int t = 0; t < 16; t++) v[t] = g4[(size_t)idx[t] * 4 + lg];
#pragma unroll
        for (int t = 0; t < 16; t++) ACCV(v[t]);
    }
    for (; j + 4 <= e; j += 4) {
        int idx[4];
#pragma unroll
        for (int t = 0; t < 4; t++) idx[t] = csr_src[j + t];
        uint4 v[4];
#pragma unroll
        for (int t = 0; t < 4; t++) v[t] = g4[(size_t)idx[t] * 4 + lg];
#pragma unroll
        for (int t = 0; t < 4; t++) ACCV(v[t]);
    }
    for (; j < e; j++) {
        uint4 v = g4[(size_t)csr_src[j] * 4 + lg];
        ACCV(v);
    }
#undef ACCV
#undef D4

    const float d = dinv[row];
    float h[16];
#pragma unroll
    for (int i = 0; i < 16; i++) {
        float a = d * acc[i] + bias[lg * 16 + i];
        if (do_relu) a = fmaxf(a, 0.0f);
        h[i] = a;
    }
    uint4 o;
    o.x = pack4_fp8(h[0], h[1], h[2], h[3]);
    o.y = pack4_fp8(h[4], h[5], h[6], h[7]);
    o.z = pack4_fp8(h[8], h[9], h[10], h[11]);
    o.w = pack4_fp8(h[12], h[13], h[14], h[15]);
    ((uint4*)out)[(size_t)row * 4 + lg] = o;
}

// ---------------- fused final agg + mean-pool ----------------
// Block = 64 rows (spans <=2 graphs). h never hits global; column partials
// atomicAdd into pre-zeroed fp32 emb (2-3 adds per element). decinit applies /NPG.
__global__ __launch_bounds__(256) void agg_pool_kernel(const unsigned int* __restrict__ g,
                                                       const int* __restrict__ row_ptr,
                                                       const int* __restrict__ csr_src,
                                                       const float* __restrict__ dinv,
                                                       const float* __restrict__ bias,
                                                       float* __restrict__ emb, int N) {
    __shared__ float hs[64][68];
    const int tid = threadIdx.x;
    const int sub = tid >> 2;
    const int lg = tid & 3;
    const int row = blockIdx.x * 64 + sub;

    const uint4* g4 = (const uint4*)g;
    float acc[16] = {};

#define D4c(u, i0) do { \
    f32x2 lo = __builtin_amdgcn_cvt_pk_f32_fp8((int)(u), false); \
    f32x2 hi = __builtin_amdgcn_cvt_pk_f32_fp8((int)(u), true); \
    acc[i0 + 0] += lo[0]; acc[i0 + 1] += lo[1]; \
    acc[i0 + 2] += hi[0]; acc[i0 + 3] += hi[1]; } while (0)
#define ACCVc(vv) do { D4c(vv.x, 0); D4c(vv.y, 4); D4c(vv.z, 8); D4c(vv.w, 12); } while (0)

    {
        uint4 v = g4[(size_t)row * 4 + lg];
        ACCVc(v);
    }
    const int s = row_ptr[row];
    const int e = row_ptr[row + 1];
    int j = s;
    for (; j + 8 <= e; j += 8) {
        int idx[8];
#pragma unroll
        for (int t = 0; t < 8; t++) idx[t] = csr_src[j + t];
        uint4 v[8];
#pragma unroll
        for (int t = 0; t < 8; t++) v[t] = g4[(size_t)idx[t] * 4 + lg];
#pragma unroll
        for (int t = 0; t < 8; t++) ACCVc(v[t]);
    }
    for (; j + 2 <= e; j += 2) {
        int i0 = csr_src[j + 0], i1 = csr_src[j + 1];
        uint4 v0 = g4[(size_t)i0 * 4 + lg];
        uint4 v1 = g4[(size_t)i1 * 4 + lg];
        ACCVc(v0); ACCVc(v1);
    }
    if (j < e) {
        uint4 v = g4[(size_t)csr_src[j] * 4 + lg];
        ACCVc(v);
    }
#undef ACCVc
#undef D4c

    {   // h = d*acc + b (no relu, last encoder layer) -> LDS fp32
        const float d = dinv[row];
        float* hrow = &hs[sub][lg * 16];
#pragma unroll
        for (int i = 0; i < 16; i++)
            hrow[i] = d * acc[i] + bias[lg * 16 + i];
    }
    __syncthreads();

    if (tid < 64) {
        const int r0 = blockIdx.x * 64;
        const int g0 = r0 / NPG;
        int bnd = (g0 + 1) * NPG - r0;
        if (bnd > 64) bnd = 64;
        float sA = 0.f, sB = 0.f;
        for (int r = 0; r < 64; r++) {
            float v = hs[r][tid];
            if (r < bnd) sA += v; else sB += v;
        }
        atomicAdd(&emb[g0 * HID + tid], sA);
        if (bnd < 64) atomicAdd(&emb[(g0 + 1) * HID + tid], sB);
    }
}

// ---------------- decoder init: t = (emb/NPG @ Wt + bt) @ W1, one wave per graph ----------------
__global__ void decinit_kernel(const float* __restrict__ emb, const float* __restrict__ Wt,
                               const float* __restrict__ bt, const float* __restrict__ W1,
                               float* __restrict__ t, int NG) {
    int wid = (blockIdx.x * 256 + threadIdx.x) >> 6;
    int lane = threadIdx.x & 63;
    if (wid >= NG) return;
    float e = emb[wid * HID + lane] * (1.0f / NPG);
    float acc = bt[lane];
    for (int k = 0; k < HID; k++) acc += __shfl(e, k) * Wt[k * HID + lane];
    float tv = 0.0f;
    for (int k = 0; k < HID; k++) tv += __shfl(acc, k) * W1[k * HID + lane];
    t[wid * HID + lane] = tv;
}

// ---------------- launch ----------------

extern "C" void kernel_launch(void* const* d_in, const int* in_sizes, int n_in,
                              void* d_out, int out_size, void* d_ws, size_t ws_size,
                              hipStream_t stream) {
    const float* x      = (const float*)d_in[0];
    const int*   edge   = (const int*)d_in[1];
    const float* enc_W1 = (const float*)d_in[3];
    const float* enc_b1 = (const float*)d_in[4];
    const float* enc_W2 = (const float*)d_in[5];
    const float* enc_b2 = (const float*)d_in[6];
    const float* enc_W3 = (const float*)d_in[7];
    const float* enc_b3 = (const float*)d_in[8];
    const float* dec_Wt = (const float*)d_in[9];
    const float* dec_bt = (const float*)d_in[10];
    const float* dec_W1 = (const float*)d_in[11];
    const float* dec_b1 = (const float*)d_in[12];
    const float* dec_W2 = (const float*)d_in[13];
    const float* dec_b2 = (const float*)d_in[14];
    const float* dec_W3 = (const float*)d_in[15];
    const float* dec_b3 = (const float*)d_in[16];
    const float* out_W  = (const float*)d_in[17];
    const float* out_b  = (const float*)d_in[18];

    const int N  = in_sizes[0] / 128;  // 200000
    const int E  = in_sizes[1] / 2;    // 3200000
    const int NG = N / NPG;            // 2000
    const int NBIN = (N + CMASK) >> CSHIFT;  // 196
    const int* esrc = edge;
    const int* edst = edge + E;

    char* w = (char*)d_ws;
    auto alloc = [&](size_t bytes) -> void* {
        void* p = (void*)w;
        w += (bytes + 255) & ~(size_t)255;
        return p;
    };
    float* bufA    = (float*)alloc((size_t)N * HID * 4);   // fp8 g_a/g_b (encoder) / bf16 g2 (decoder)
    int*   csr     = (int*)alloc((size_t)E * 4);
    int*   row_ptr = (int*)alloc((size_t)(N + 1) * 4);
    int*   cnt     = (int*)alloc((size_t)N * 4);
    float* dinv    = (float*)alloc((size_t)N * 4);
    int*   partials= (int*)alloc(1024);
    float* emb     = (float*)alloc((size_t)NG * HID * 4);
    float* tbuf    = (float*)alloc((size_t)NG * HID * 4);
    int*   gcur    = (int*)alloc((size_t)NBIN * 16 * 4);
    int*   stage   = (int*)alloc((size_t)NBIN * SLOT * 4);  // 25.69 MB; reused as g3 (bf16)

    unsigned char* g_a = (unsigned char*)bufA;                       // 12.8 MB fp8
    unsigned char* g_b = (unsigned char*)bufA + (size_t)N * HID;     // 12.8 MB fp8
    unsigned short* g3 = (unsigned short*)stage;  // CSR staging dead after encoder

    const int NB = (N + 2047) / 2048;
    const int GB = 1024;  // gemm blocks (4 waves each)

    // CSR build: LDS-binned two-phase, no random global atomics
    zero_int_kernel<<<(NBIN * 16 + 255) / 256, 256, 0, stream>>>(gcur, NBIN * 16);
    bin1_kernel<<<(E + TILE - 1) / TILE, 256, 0, stream>>>(esrc, edst, gcur, stage, E, NBIN);
    bin_count_kernel<<<NBIN, 256, 0, stream>>>(gcur, stage, cnt, dinv, N);
    scan1_kernel<<<NB, 256, 0, stream>>>(cnt, row_ptr, partials, N);
    scan2_kernel<<<1, 128, 0, stream>>>(partials, NB);
    scan3_kernel<<<NB, 256, 0, stream>>>(row_ptr, partials, N, E);
    bin_fill_kernel<<<NBIN, 256, 0, stream>>>(gcur, stage, row_ptr, csr, N);

    // encoder: gemm1 -> g_a; {agg (fp8 h) + small fp8-A gemm} x2; fused final agg+pool -> emb
    zero_int_kernel<<<(NG * HID + 255) / 256, 256, 0, stream>>>((int*)emb, NG * HID);
    mfma_gemm<128, 64, 1, false, 0, 1, 2><<<GB, 256, 0, stream>>>(x, enc_W1, nullptr, dinv, nullptr,
                                                                  (float*)g_a, N);
    agg_f8_kernel<<<N / 64, 256, 0, stream>>>((const unsigned*)g_a, row_ptr, csr, dinv, enc_b1,
                                              (unsigned*)g_b, N, 1);
    mfma_gemm<64, 64, 1, false, 5, 1, 2><<<GB, 256, 0, stream>>>((const float*)g_b, enc_W2, nullptr,
                                                                 dinv, nullptr, (float*)g_a, N);
    agg_f8_kernel<<<N / 64, 256, 0, stream>>>((const unsigned*)g_a, row_ptr, csr, dinv, enc_b2,
                                              (unsigned*)g_b, N, 1);
    mfma_gemm<64, 64, 1, false, 5, 1, 2><<<GB, 256, 0, stream>>>((const float*)g_b, enc_W3, nullptr,
                                                                 dinv, nullptr, (float*)g_a, N);
    agg_pool_kernel<<<N / 64, 256, 0, stream>>>((const unsigned*)g_a, row_ptr, csr, dinv, enc_b3,
                                                emb, N);

    // decoder head
    decinit_kernel<<<(NG * 64 + 255) / 256, 256, 0, stream>>>(emb, dec_Wt, dec_bt, dec_W1, tbuf, NG);

    // decoder as 3 GEMMs with fused A-construction (bf16 intermediates):
    mfma_gemm<64, 64, 2, false, 2, 2, 1><<<GB, 256, 0, stream>>>(tbuf, dec_W2, nullptr, nullptr,
                                                                 dec_b1, bufA, N);
    mfma_gemm<64, 64, 2, false, 4, 2, 1><<<GB, 256, 0, stream>>>(bufA, dec_W3, nullptr, nullptr,
                                                                 dec_b2, (float*)g3, N);
    mfma_gemm<64, 128, 0, true, 4, 2, 0><<<GB, 256, 0, stream>>>((const float*)g3, out_W, out_b, nullptr,
                                                                 dec_b3, (float*)d_out, N);
}

// Round 13
// 421.749 us; speedup vs baseline: 1.0366x; 1.0366x over previous
//
#include <hip/hip_runtime.h>
#include <hip/hip_bf16.h>
#include <cstdint>

#define HID 64
#define NPG 100

// coarse buckets for CSR build: 1024 dsts per bucket
#define CSHIFT 10
#define CMASK ((1 << CSHIFT) - 1)
#define CAP 56          // LDS slots per bin per tile (λ≈42, spill ~1%)
#define TILE 8192       // edges per phase-1 block
#define SLOT 32768      // staging ints per bucket (mean ~16.6k, 2x slack)

typedef short bf16x8 __attribute__((ext_vector_type(8)));
typedef float f32x4 __attribute__((ext_vector_type(4)));
typedef float f32x2 __attribute__((ext_vector_type(2)));

__device__ __forceinline__ unsigned short bf16_rn(float f) {
    union { float f; unsigned u; } c; c.f = f;
    unsigned r = c.u + 0x7fffu + ((c.u >> 16) & 1u);
    return (unsigned short)(r >> 16);
}
__device__ __forceinline__ float bf16_f(unsigned short h) {
    union { unsigned u; float f; } c; c.u = ((unsigned)h) << 16;
    return c.f;
}
__device__ __forceinline__ float f_lo(unsigned u) {
    union { unsigned u; float f; } c; c.u = u << 16;
    return c.f;
}
__device__ __forceinline__ float f_hi(unsigned u) {
    union { unsigned u; float f; } c; c.u = u & 0xffff0000u;
    return c.f;
}
__device__ __forceinline__ unsigned pack4_fp8(float a, float b, float c, float d) {
    int r = __builtin_amdgcn_cvt_pk_fp8_f32(a, b, 0, false);
    r = __builtin_amdgcn_cvt_pk_fp8_f32(c, d, r, true);
    return (unsigned)r;
}

// decoder chain-graph degree
__device__ __forceinline__ float dinvdec(int p) {
    int d = (p >= 1) + (p >= 2) + (p <= NPG - 2) + (p <= NPG - 3);
    return rsqrtf((float)(d + 1));
}

// ---------------- CSR build (LDS-binned, no cross-XCD line sharing) ----------------

__global__ void zero_int_kernel(int* __restrict__ p, int n) {
    int i = blockIdx.x * 256 + threadIdx.x;
    if (i < n) p[i] = 0;
}

__global__ __launch_bounds__(256) void bin1_kernel(const int* __restrict__ src,
                                                   const int* __restrict__ dst,
                                                   int* __restrict__ gcur,
                                                   int* __restrict__ stage,
                                                   int E, int nbin) {
    __shared__ int bins[256][CAP];
    __shared__ int bcnt[256];
    const int tid = threadIdx.x;
    bcnt[tid] = 0;
    __syncthreads();

    const int e0 = blockIdx.x * TILE;
    const int cnt = min(TILE, E - e0);
    for (int i = tid; i < cnt; i += 256) {
        int s = src[e0 + i], d = dst[e0 + i];
        int b = d >> CSHIFT;
        int v = (s << CSHIFT) | (d & CMASK);
        int pos = atomicAdd(&bcnt[b], 1);
        if (pos < CAP) {
            bins[b][pos] = v;
        } else {  // rare spill: private 4-slot chunk, -1 pads
            int g = atomicAdd(&gcur[b * 16], 4);
            int* sp = stage + (size_t)b * SLOT + g;
            sp[0] = v; sp[1] = -1; sp[2] = -1; sp[3] = -1;
        }
    }
    __syncthreads();

    if (tid < nbin) {
        int c = min(bcnt[tid], CAP);
        int r = (c + 3) & ~3;
        if (r > 0) {
            int base = atomicAdd(&gcur[tid * 16], r);
            int* dstp = stage + (size_t)tid * SLOT + base;
            for (int j = 0; j < r; j += 4) {
                int4 v;
                v.x = (j + 0 < c) ? bins[tid][j + 0] : -1;
                v.y = (j + 1 < c) ? bins[tid][j + 1] : -1;
                v.z = (j + 2 < c) ? bins[tid][j + 2] : -1;
                v.w = (j + 3 < c) ? bins[tid][j + 3] : -1;
                *(int4*)(dstp + j) = v;
            }
        }
    }
}

__global__ __launch_bounds__(256) void bin_count_kernel(const int* __restrict__ gcur,
                                                        const int* __restrict__ stage,
                                                        int* __restrict__ cntg,
                                                        float* __restrict__ dinvg, int N) {
    __shared__ int lc[1 << CSHIFT];
    const int b = blockIdx.x;
    for (int j = threadIdx.x; j < (1 << CSHIFT); j += 256) lc[j] = 0;
    __syncthreads();
    const int len = gcur[b * 16];
    const int* sp = stage + (size_t)b * SLOT;
    for (int i = threadIdx.x; i < len; i += 256) {
        int v = sp[i];
        if (v >= 0) atomicAdd(&lc[v & CMASK], 1);
    }
    __syncthreads();
    const int d0 = b << CSHIFT;
    for (int j = threadIdx.x; j < (1 << CSHIFT); j += 256) {
        int d = d0 + j;
        if (d < N) {
            int c = lc[j];
            cntg[d] = c;
            dinvg[d] = rsqrtf((float)c + 1.0f);
        }
    }
}

__global__ __launch_bounds__(256) void scan1_kernel(const int* __restrict__ cnt,
                                                    int* __restrict__ row_ptr,
                                                    int* __restrict__ partials, int N) {
    __shared__ int sd[256];
    int tid = threadIdx.x;
    int base = blockIdx.x * 2048 + tid * 8;
    int v[8];
    int s = 0;
#pragma unroll
    for (int j = 0; j < 8; j++) {
        int i = base + j;
        int t = (i < N) ? cnt[i] : 0;
        v[j] = t; s += t;
    }
    sd[tid] = s;
    __syncthreads();
    for (int off = 1; off < 256; off <<= 1) {
        int t = (tid >= off) ? sd[tid - off] : 0;
        __syncthreads();
        sd[tid] += t;
        __syncthreads();
    }
    int run = sd[tid] - s;  // exclusive within block
#pragma unroll
    for (int j = 0; j < 8; j++) {
        int i = base + j;
        if (i < N) row_ptr[i] = run;
        run += v[j];
    }
    if (tid == 0) partials[blockIdx.x] = sd[255];
}

__global__ void scan2_kernel(int* __restrict__ partials, int nb) {
    __shared__ int sd[128];
    int tid = threadIdx.x;
    int v = (tid < nb) ? partials[tid] : 0;
    sd[tid] = v;
    __syncthreads();
    for (int off = 1; off < 128; off <<= 1) {
        int t = (tid >= off) ? sd[tid - off] : 0;
        __syncthreads();
        sd[tid] += t;
        __syncthreads();
    }
    if (tid < nb) partials[tid] = sd[tid] - v;
}

__global__ void scan3_kernel(int* __restrict__ row_ptr, const int* __restrict__ partials,
                             int N, int E) {
    int base = blockIdx.x * 2048 + threadIdx.x * 8;
    int add = partials[blockIdx.x];
#pragma unroll
    for (int j = 0; j < 8; j++) {
        int i = base + j;
        if (i < N) row_ptr[i] += add;
    }
    if (blockIdx.x == 0 && threadIdx.x == 0) row_ptr[N] = E;
}

__global__ __launch_bounds__(256) void bin_fill_kernel(const int* __restrict__ gcur,
                                                       const int* __restrict__ stage,
                                                       const int* __restrict__ row_ptr,
                                                       int* __restrict__ csr_src, int N) {
    __shared__ int cur[1 << CSHIFT];
    __shared__ int rp[1 << CSHIFT];
    const int b = blockIdx.x;
    const int d0 = b << CSHIFT;
    for (int j = threadIdx.x; j < (1 << CSHIFT); j += 256) {
        cur[j] = 0;
        int d = d0 + j;
        rp[j] = (d < N) ? row_ptr[d] : 0;
    }
    __syncthreads();
    const int len = gcur[b * 16];
    const int* sp = stage + (size_t)b * SLOT;
    for (int i = threadIdx.x; i < len; i += 256) {
        int v = sp[i];
        if (v >= 0) {
            int dl = v & CMASK;
            int pos = rp[dl] + atomicAdd(&cur[dl], 1);
            csr_src[pos] = v >> CSHIFT;
        }
    }
}

// ---------------- MFMA GEMM ----------------
// AMODE: 0 = fp32 A direct; 1 = packed bf16 A direct;
//        2 = closed-form decoder z1 (A = tbuf [NG][64], apre = b1);
//        3 = stencil over fp32 g; 4 = stencil over bf16 g;
//        5 = packed fp8 e4m3 A (decode in-reg).
// WP: 1 = plain bf16 W (1 MFMA), 2 = hi/lo split W+A (3 MFMA, fp32-grade).
// OMODE: 0 = fp32 out, 1 = packed bf16 out, 2 = packed fp8 e4m3 out.
template <int K, int N, int SCALE_MODE, bool BIAS, int AMODE, int WP, int OMODE>
__global__ __launch_bounds__(256, 2) void mfma_gemm(const float* __restrict__ A,
                                                    const float* __restrict__ W,
                                                    const float* __restrict__ bias,
                                                    const float* __restrict__ rowscale,
                                                    const float* __restrict__ apre,
                                                    float* __restrict__ out, int M) {
    constexpr int KP = K + 8;
    constexpr int NT = N / 16;
    constexpr int KS = K / 32;
    __shared__ unsigned short Wt[WP][N][KP];
    const int tid = threadIdx.x;

    for (int idx = tid; idx < K * N; idx += 256) {
        float w = W[idx];
        int k = idx / N, n = idx % N;  // N is pow2
        unsigned short h = bf16_rn(w);
        Wt[0][n][k] = h;
        if (WP == 2) Wt[1][n][k] = bf16_rn(w - bf16_f(h));
    }
    __syncthreads();

    const int lane = tid & 63;
    const int l15 = lane & 15;
    const int lg = lane >> 4;  // 0..3
    const int nstrips = M / 16;
    const int wglobal = blockIdx.x * 4 + (tid >> 6);
    const int wtotal = gridDim.x * 4;

    float curf[AMODE != 1 ? KS * 8 : 1], nxtf[AMODE != 1 ? KS * 8 : 1];
    uint4 curv[AMODE == 1 ? KS : 1], nxtv[AMODE == 1 ? KS : 1];

    // pre-bias (A-construction bias) for modes 2/3/4 — constant across strips
    float preb[(AMODE >= 2 && AMODE <= 4) ? KS * 8 : 1];
    if (AMODE >= 2 && AMODE <= 4) {
#pragma unroll
        for (int ks = 0; ks < KS; ks++)
#pragma unroll
            for (int j = 0; j < 8; j++) preb[ks * 8 + j] = apre[ks * 32 + lg * 8 + j];
    }

    auto loadA_f = [&](int s, float* dstv) {
        const float* arow = A + (size_t)(s * 16 + l15) * K + lg * 8;
#pragma unroll
        for (int ks = 0; ks < KS; ks++) {
            float4 a = *(const float4*)(arow + ks * 32);
            float4 b = *(const float4*)(arow + ks * 32 + 4);
            dstv[ks * 8 + 0] = a.x; dstv[ks * 8 + 1] = a.y;
            dstv[ks * 8 + 2] = a.z; dstv[ks * 8 + 3] = a.w;
            dstv[ks * 8 + 4] = b.x; dstv[ks * 8 + 5] = b.y;
            dstv[ks * 8 + 6] = b.z; dstv[ks * 8 + 7] = b.w;
        }
    };
    auto loadA_h = [&](int s, uint4* dstv) {
        const unsigned short* arow = (const unsigned short*)A + (size_t)(s * 16 + l15) * K + lg * 8;
#pragma unroll
        for (int ks = 0; ks < KS; ks++)
            dstv[ks] = *(const uint4*)(arow + ks * 32);
    };
    // mode 5: packed fp8 A -> decode to fp32
    auto loadA_f8 = [&](int s, float* dstv) {
        const unsigned char* arow = (const unsigned char*)A + (size_t)(s * 16 + l15) * K + lg * 8;
#pragma unroll
        for (int ks = 0; ks < KS; ks++) {
            uint2 v = *(const uint2*)(arow + ks * 32);
            f32x2 a0 = __builtin_amdgcn_cvt_pk_f32_fp8((int)v.x, false);
            f32x2 a1 = __builtin_amdgcn_cvt_pk_f32_fp8((int)v.x, true);
            f32x2 a2 = __builtin_amdgcn_cvt_pk_f32_fp8((int)v.y, false);
            f32x2 a3 = __builtin_amdgcn_cvt_pk_f32_fp8((int)v.y, true);
            dstv[ks * 8 + 0] = a0[0]; dstv[ks * 8 + 1] = a0[1];
            dstv[ks * 8 + 2] = a1[0]; dstv[ks * 8 + 3] = a1[1];
            dstv[ks * 8 + 4] = a2[0]; dstv[ks * 8 + 5] = a2[1];
            dstv[ks * 8 + 6] = a3[0]; dstv[ks * 8 + 7] = a3[1];
        }
    };
    // mode 2: z1 closed form from tbuf
    auto loadA_z1 = [&](int s, float* dstv) {
        int grow = s * 16 + l15;
        int gph = grow / NPG;
        int p = grow - gph * NPG;
        float dp = dinvdec(p);
        float qs = dp;
        if (p >= 1) qs += dinvdec(p - 1);
        if (p >= 2) qs += dinvdec(p - 2);
        if (p <= NPG - 2) qs += dinvdec(p + 1);
        if (p <= NPG - 3) qs += dinvdec(p + 2);
        float sc = dp * qs;
#pragma unroll
        for (int ks = 0; ks < KS; ks++) {
            const float* tr = A + gph * HID + ks * 32 + lg * 8;
            float4 a = *(const float4*)tr;
            float4 b = *(const float4*)(tr + 4);
            float av[8] = {a.x, a.y, a.z, a.w, b.x, b.y, b.z, b.w};
#pragma unroll
            for (int j = 0; j < 8; j++)
                dstv[ks * 8 + j] = fmaxf(sc * av[j] + preb[ks * 8 + j], 0.f);
        }
    };
    // modes 3/4: 5-point stencil over g (fp32 or bf16) + bias + relu
    auto loadA_st = [&](int s, float* dstv) {
        int grow = s * 16 + l15;
        int gph = grow / NPG;
        int p = grow - gph * NPG;
        float dd = dinvdec(p);
#pragma unroll
        for (int ks = 0; ks < KS; ks++) {
            float acc8[8] = {0.f, 0.f, 0.f, 0.f, 0.f, 0.f, 0.f, 0.f};
            const int cb = ks * 32 + lg * 8;
            if (AMODE == 3) {
                const float* base = A + (size_t)grow * K + cb;
                auto addr = [&](const float* rp) {
                    float4 a = *(const float4*)rp;
                    float4 b = *(const float4*)(rp + 4);
                    acc8[0] += a.x; acc8[1] += a.y; acc8[2] += a.z; acc8[3] += a.w;
                    acc8[4] += b.x; acc8[5] += b.y; acc8[6] += b.z; acc8[7] += b.w;
                };
                addr(base);
                if (p >= 1) addr(base - K);
                if (p >= 2) addr(base - 2 * K);
                if (p <= NPG - 2) addr(base + K);
                if (p <= NPG - 3) addr(base + 2 * K);
            } else {
                const unsigned short* base = (const unsigned short*)A + (size_t)grow * K + cb;
                auto addr = [&](const unsigned short* rp) {
                    uint4 v = *(const uint4*)rp;
                    acc8[0] += f_lo(v.x); acc8[1] += f_hi(v.x);
                    acc8[2] += f_lo(v.y); acc8[3] += f_hi(v.y);
                    acc8[4] += f_lo(v.z); acc8[5] += f_hi(v.z);
                    acc8[6] += f_lo(v.w); acc8[7] += f_hi(v.w);
                };
                addr(base);
                if (p >= 1) addr(base - K);
                if (p >= 2) addr(base - 2 * K);
                if (p <= NPG - 2) addr(base + K);
                if (p <= NPG - 3) addr(base + 2 * K);
            }
#pragma unroll
            for (int j = 0; j < 8; j++)
                dstv[ks * 8 + j] = fmaxf(dd * acc8[j] + preb[ks * 8 + j], 0.f);
        }
    };

    auto loadA = [&](int s) {
        if (AMODE == 0) loadA_f(s, nxtf);
        else if (AMODE == 1) loadA_h(s, nxtv);
        else if (AMODE == 2) loadA_z1(s, nxtf);
        else if (AMODE == 5) loadA_f8(s, nxtf);
        else loadA_st(s, nxtf);
    };

    int s = wglobal;
    if (s < nstrips) {
        loadA(s);
        if (AMODE == 1) { for (int i = 0; i < KS; i++) curv[i] = nxtv[i]; }
        else            { for (int i = 0; i < KS * 8; i++) curf[i] = nxtf[i]; }
    }
    for (; s < nstrips; s += wtotal) {
        int sn = s + wtotal;
        if (sn < nstrips) loadA(sn);

        f32x4 acc[NT];
#pragma unroll
        for (int t = 0; t < NT; t++) acc[t] = f32x4{0.f, 0.f, 0.f, 0.f};

#pragma unroll
        for (int ks = 0; ks < KS; ks++) {
            bf16x8 ah, al;
            if (AMODE == 1) {
                ah = *(bf16x8*)&curv[ks];
            } else {
#pragma unroll
                for (int j = 0; j < 8; j++) {
                    float v = curf[ks * 8 + j];
                    unsigned short h = bf16_rn(v);
                    ah[j] = (short)h;
                    if (WP == 2) al[j] = (short)bf16_rn(v - bf16_f(h));
                }
            }
            const int k0 = ks * 32 + lg * 8;
#pragma unroll
            for (int t = 0; t < NT; t++) {
                int n = t * 16 + l15;
                bf16x8 bh = *(const bf16x8*)&Wt[0][n][k0];
                acc[t] = __builtin_amdgcn_mfma_f32_16x16x32_bf16(ah, bh, acc[t], 0, 0, 0);
                if (WP == 2) {
                    bf16x8 bl = *(const bf16x8*)&Wt[1][n][k0];
                    acc[t] = __builtin_amdgcn_mfma_f32_16x16x32_bf16(ah, bl, acc[t], 0, 0, 0);
                    acc[t] = __builtin_amdgcn_mfma_f32_16x16x32_bf16(al, bh, acc[t], 0, 0, 0);
                }
            }
        }

#pragma unroll
        for (int r = 0; r < 4; r++) {
            int row = s * 16 + lg * 4 + r;
            float scale = 1.0f;
            if (SCALE_MODE == 1) scale = rowscale[row];
            if (SCALE_MODE == 2) scale = dinvdec(row % NPG);
#pragma unroll
            for (int t = 0; t < NT; t++) {
                float o = acc[t][r] * scale;
                if (BIAS) o += bias[t * 16 + l15];
                if (OMODE == 2) {
                    int p = __builtin_amdgcn_cvt_pk_fp8_f32(o, 0.0f, 0, false);
                    ((unsigned char*)out)[(size_t)row * N + t * 16 + l15] = (unsigned char)(p & 0xff);
                } else if (OMODE == 1) {
                    ((unsigned short*)out)[(size_t)row * N + t * 16 + l15] = bf16_rn(o);
                } else {
                    out[(size_t)row * N + t * 16 + l15] = o;
                }
            }
        }
        if (AMODE == 1) {
#pragma unroll
            for (int i = 0; i < KS; i++) curv[i] = nxtv[i];
        } else {
#pragma unroll
            for (int i = 0; i < KS * 8; i++) curf[i] = nxtf[i];
        }
    }
}

// ---------------- encoder aggregation (gather over CSR, fp8 rows -> fp8 h) ----------------
// Barrier-free; 4 lanes/row (uint4 = 16 fp8); 8-deep pipeline (VGPR ~80, occupancy-friendly).
// out: h = relu?(dinv*sum + bias) packed fp8.
__global__ __launch_bounds__(256) void agg_f8_kernel(const unsigned int* __restrict__ g,
                                                     const int* __restrict__ row_ptr,
                                                     const int* __restrict__ csr_src,
                                                     const float* __restrict__ dinv,
                                                     const float* __restrict__ bias,
                                                     unsigned int* __restrict__ out,
                                                     int N, int do_relu) {
    const int tid = threadIdx.x;
    const int sub = tid >> 2;        // 0..63: row within block
    const int lg = tid & 3;          // 16B group (16 fp8 values)
    const int row = blockIdx.x * 64 + sub;
    if (row >= N) return;

    const uint4* g4 = (const uint4*)g;
    float acc[16] = {};

#define D4(u, i0) do { \
    f32x2 lo = __builtin_amdgcn_cvt_pk_f32_fp8((int)(u), false); \
    f32x2 hi = __builtin_amdgcn_cvt_pk_f32_fp8((int)(u), true); \
    acc[i0 + 0] += lo[0]; acc[i0 + 1] += lo[1]; \
    acc[i0 + 2] += hi[0]; acc[i0 + 3] += hi[1]; } while (0)
#define ACCV(vv) do { D4(vv.x, 0); D4(vv.y, 4); D4(vv.z, 8); D4(vv.w, 12); } while (0)

    {   // self term
        uint4 v = g4[(size_t)row * 4 + lg];
        ACCV(v);
    }

    const int s = row_ptr[row];
    const int e = row_ptr[row + 1];
    int j = s;

    for (; j + 8 <= e; j += 8) {
        int idx[8];
#pragma unroll
        for (int t = 0; t < 8; t++) idx[t] = csr_src[j + t];
        uint4 v[8];
#pragma unroll
        for (int t = 0; t < 8; t++) v[t] = g4[(size_t)idx[t] * 4 + lg];
#pragma unroll
        for (int t = 0; t < 8; t++) ACCV(v[t]);
    }
    for (; j + 2 <= e; j += 2) {
        int i0 = csr_src[j + 0], i1 = csr_src[j + 1];
        uint4 v0 = g4[(size_t)i0 * 4 + lg];
        uint4 v1 = g4[(size_t)i1 * 4 + lg];
        ACCV(v0); ACCV(v1);
    }
    if (j < e) {
        uint4 v = g4[(size_t)csr_src[j] * 4 + lg];
        ACCV(v);
    }
#undef ACCV
#undef D4

    const float d = dinv[row];
    float h[16];
#pragma unroll
    for (int i = 0; i < 16; i++) {
        float a = d * acc[i] + bias[lg * 16 + i];
        if (do_relu) a = fmaxf(a, 0.0f);
        h[i] = a;
    }
    uint4 o;
    o.x = pack4_fp8(h[0], h[1], h[2], h[3]);
    o.y = pack4_fp8(h[4], h[5], h[6], h[7]);
    o.z = pack4_fp8(h[8], h[9], h[10], h[11]);
    o.w = pack4_fp8(h[12], h[13], h[14], h[15]);
    ((uint4*)out)[(size_t)row * 4 + lg] = o;
}

// ---------------- fused final agg + mean-pool ----------------
// Block = 64 rows (spans <=2 graphs). h never hits global; column partials
// atomicAdd into pre-zeroed fp32 emb (2-3 adds per element). decinit applies /NPG.
__global__ __launch_bounds__(256) void agg_pool_kernel(const unsigned int* __restrict__ g,
                                                       const int* __restrict__ row_ptr,
                                                       const int* __restrict__ csr_src,
                                                       const float* __restrict__ dinv,
                                                       const float* __restrict__ bias,
                                                       float* __restrict__ emb, int N) {
    __shared__ float hs[64][68];
    const int tid = threadIdx.x;
    const int sub = tid >> 2;
    const int lg = tid & 3;
    const int row = blockIdx.x * 64 + sub;

    const uint4* g4 = (const uint4*)g;
    float acc[16] = {};

#define D4c(u, i0) do { \
    f32x2 lo = __builtin_amdgcn_cvt_pk_f32_fp8((int)(u), false); \
    f32x2 hi = __builtin_amdgcn_cvt_pk_f32_fp8((int)(u), true); \
    acc[i0 + 0] += lo[0]; acc[i0 + 1] += lo[1]; \
    acc[i0 + 2] += hi[0]; acc[i0 + 3] += hi[1]; } while (0)
#define ACCVc(vv) do { D4c(vv.x, 0); D4c(vv.y, 4); D4c(vv.z, 8); D4c(vv.w, 12); } while (0)

    {
        uint4 v = g4[(size_t)row * 4 + lg];
        ACCVc(v);
    }
    const int s = row_ptr[row];
    const int e = row_ptr[row + 1];
    int j = s;
    for (; j + 8 <= e; j += 8) {
        int idx[8];
#pragma unroll
        for (int t = 0; t < 8; t++) idx[t] = csr_src[j + t];
        uint4 v[8];
#pragma unroll
        for (int t = 0; t < 8; t++) v[t] = g4[(size_t)idx[t] * 4 + lg];
#pragma unroll
        for (int t = 0; t < 8; t++) ACCVc(v[t]);
    }
    for (; j + 2 <= e; j += 2) {
        int i0 = csr_src[j + 0], i1 = csr_src[j + 1];
        uint4 v0 = g4[(size_t)i0 * 4 + lg];
        uint4 v1 = g4[(size_t)i1 * 4 + lg];
        ACCVc(v0); ACCVc(v1);
    }
    if (j < e) {
        uint4 v = g4[(size_t)csr_src[j] * 4 + lg];
        ACCVc(v);
    }
#undef ACCVc
#undef D4c

    {   // h = d*acc + b (no relu, last encoder layer) -> LDS fp32
        const float d = dinv[row];
        float* hrow = &hs[sub][lg * 16];
#pragma unroll
        for (int i = 0; i < 16; i++)
            hrow[i] = d * acc[i] + bias[lg * 16 + i];
    }
    __syncthreads();

    if (tid < 64) {
        const int r0 = blockIdx.x * 64;
        const int g0 = r0 / NPG;
        int bnd = (g0 + 1) * NPG - r0;
        if (bnd > 64) bnd = 64;
        float sA = 0.f, sB = 0.f;
        for (int r = 0; r < 64; r++) {
            float v = hs[r][tid];
            if (r < bnd) sA += v; else sB += v;
        }
        atomicAdd(&emb[g0 * HID + tid], sA);
        if (bnd < 64) atomicAdd(&emb[(g0 + 1) * HID + tid], sB);
    }
}

// ---------------- decoder init: t = (emb/NPG @ Wt + bt) @ W1, one wave per graph ----------------
__global__ void decinit_kernel(const float* __restrict__ emb, const float* __restrict__ Wt,
                               const float* __restrict__ bt, const float* __restrict__ W1,
                               float* __restrict__ t, int NG) {
    int wid = (blockIdx.x * 256 + threadIdx.x) >> 6;
    int lane = threadIdx.x & 63;
    if (wid >= NG) return;
    float e = emb[wid * HID + lane] * (1.0f / NPG);
    float acc = bt[lane];
    for (int k = 0; k < HID; k++) acc += __shfl(e, k) * Wt[k * HID + lane];
    float tv = 0.0f;
    for (int k = 0; k < HID; k++) tv += __shfl(acc, k) * W1[k * HID + lane];
    t[wid * HID + lane] = tv;
}

// ---------------- launch ----------------

extern "C" void kernel_launch(void* const* d_in, const int* in_sizes, int n_in,
                              void* d_out, int out_size, void* d_ws, size_t ws_size,
                              hipStream_t stream) {
    const float* x      = (const float*)d_in[0];
    const int*   edge   = (const int*)d_in[1];
    const float* enc_W1 = (const float*)d_in[3];
    const float* enc_b1 = (const float*)d_in[4];
    const float* enc_W2 = (const float*)d_in[5];
    const float* enc_b2 = (const float*)d_in[6];
    const float* enc_W3 = (const float*)d_in[7];
    const float* enc_b3 = (const float*)d_in[8];
    const float* dec_Wt = (const float*)d_in[9];
    const float* dec_bt = (const float*)d_in[10];
    const float* dec_W1 = (const float*)d_in[11];
    const float* dec_b1 = (const float*)d_in[12];
    const float* dec_W2 = (const float*)d_in[13];
    const float* dec_b2 = (const float*)d_in[14];
    const float* dec_W3 = (const float*)d_in[15];
    const float* dec_b3 = (const float*)d_in[16];
    const float* out_W  = (const float*)d_in[17];
    const float* out_b  = (const float*)d_in[18];

    const int N  = in_sizes[0] / 128;  // 200000
    const int E  = in_sizes[1] / 2;    // 3200000
    const int NG = N / NPG;            // 2000
    const int NBIN = (N + CMASK) >> CSHIFT;  // 196
    const int* esrc = edge;
    const int* edst = edge + E;

    char* w = (char*)d_ws;
    auto alloc = [&](size_t bytes) -> void* {
        void* p = (void*)w;
        w += (bytes + 255) & ~(size_t)255;
        return p;
    };
    float* bufA    = (float*)alloc((size_t)N * HID * 4);   // fp8 g_a/g_b (encoder) / bf16 g2 (decoder)
    int*   csr     = (int*)alloc((size_t)E * 4);
    int*   row_ptr = (int*)alloc((size_t)(N + 1) * 4);
    int*   cnt     = (int*)alloc((size_t)N * 4);
    float* dinv    = (float*)alloc((size_t)N * 4);
    int*   partials= (int*)alloc(1024);
    float* emb     = (float*)alloc((size_t)NG * HID * 4);
    float* tbuf    = (float*)alloc((size_t)NG * HID * 4);
    int*   gcur    = (int*)alloc((size_t)NBIN * 16 * 4);
    int*   stage   = (int*)alloc((size_t)NBIN * SLOT * 4);  // 25.69 MB; reused as g3 (bf16)

    unsigned char* g_a = (unsigned char*)bufA;                       // 12.8 MB fp8
    unsigned char* g_b = (unsigned char*)bufA + (size_t)N * HID;     // 12.8 MB fp8
    unsigned short* g3 = (unsigned short*)stage;  // CSR staging dead after encoder

    const int NB = (N + 2047) / 2048;
    const int GB = 1024;  // gemm blocks (4 waves each)

    // CSR build: LDS-binned two-phase, no random global atomics
    zero_int_kernel<<<(NBIN * 16 + 255) / 256, 256, 0, stream>>>(gcur, NBIN * 16);
    bin1_kernel<<<(E + TILE - 1) / TILE, 256, 0, stream>>>(esrc, edst, gcur, stage, E, NBIN);
    bin_count_kernel<<<NBIN, 256, 0, stream>>>(gcur, stage, cnt, dinv, N);
    scan1_kernel<<<NB, 256, 0, stream>>>(cnt, row_ptr, partials, N);
    scan2_kernel<<<1, 128, 0, stream>>>(partials, NB);
    scan3_kernel<<<NB, 256, 0, stream>>>(row_ptr, partials, N, E);
    bin_fill_kernel<<<NBIN, 256, 0, stream>>>(gcur, stage, row_ptr, csr, N);

    // encoder: gemm1 -> g_a; {agg (fp8 h) + small fp8-A gemm} x2; fused final agg+pool -> emb
    zero_int_kernel<<<(NG * HID + 255) / 256, 256, 0, stream>>>((int*)emb, NG * HID);
    mfma_gemm<128, 64, 1, false, 0, 1, 2><<<GB, 256, 0, stream>>>(x, enc_W1, nullptr, dinv, nullptr,
                                                                  (float*)g_a, N);
    agg_f8_kernel<<<N / 64, 256, 0, stream>>>((const unsigned*)g_a, row_ptr, csr, dinv, enc_b1,
                                              (unsigned*)g_b, N, 1);
    mfma_gemm<64, 64, 1, false, 5, 1, 2><<<GB, 256, 0, stream>>>((const float*)g_b, enc_W2, nullptr,
                                                                 dinv, nullptr, (float*)g_a, N);
    agg_f8_kernel<<<N / 64, 256, 0, stream>>>((const unsigned*)g_a, row_ptr, csr, dinv, enc_b2,
                                              (unsigned*)g_b, N, 1);
    mfma_gemm<64, 64, 1, false, 5, 1, 2><<<GB, 256, 0, stream>>>((const float*)g_b, enc_W3, nullptr,
                                                                 dinv, nullptr, (float*)g_a, N);
    agg_pool_kernel<<<N / 64, 256, 0, stream>>>((const unsigned*)g_a, row_ptr, csr, dinv, enc_b3,
                                                emb, N);

    // decoder head
    decinit_kernel<<<(NG * 64 + 255) / 256, 256, 0, stream>>>(emb, dec_Wt, dec_bt, dec_W1, tbuf, NG);

    // decoder as 3 GEMMs with fused A-construction (bf16 intermediates):
    mfma_gemm<64, 64, 2, false, 2, 2, 1><<<GB, 256, 0, stream>>>(tbuf, dec_W2, nullptr, nullptr,
                                                                 dec_b1, bufA, N);
    mfma_gemm<64, 64, 2, false, 4, 2, 1><<<GB, 256, 0, stream>>>(bufA, dec_W3, nullptr, nullptr,
                                                                 dec_b2, (float*)g3, N);
    mfma_gemm<64, 128, 0, true, 4, 2, 0><<<GB, 256, 0, stream>>>((const float*)g3, out_W, out_b, nullptr,
                                                                 dec_b3, (float*)d_out, N);
}

// Round 14
// 409.478 us; speedup vs baseline: 1.0676x; 1.0300x over previous
//
#include <hip/hip_runtime.h>
#include <hip/hip_bf16.h>
#include <cstdint>

#define HID 64
#define NPG 100

// coarse buckets for CSR build: 1024 dsts per bucket
#define CSHIFT 10
#define CMASK ((1 << CSHIFT) - 1)
#define CAP 56          // LDS slots per bin per tile (λ≈42, spill ~1%)
#define TILE 8192       // edges per phase-1 block
#define SLOT 32768      // staging ints per bucket (mean ~16.6k, 2x slack)

typedef short bf16x8 __attribute__((ext_vector_type(8)));
typedef float f32x4 __attribute__((ext_vector_type(4)));
typedef float f32x2 __attribute__((ext_vector_type(2)));

__device__ __forceinline__ unsigned short bf16_rn(float f) {
    union { float f; unsigned u; } c; c.f = f;
    unsigned r = c.u + 0x7fffu + ((c.u >> 16) & 1u);
    return (unsigned short)(r >> 16);
}
__device__ __forceinline__ float bf16_f(unsigned short h) {
    union { unsigned u; float f; } c; c.u = ((unsigned)h) << 16;
    return c.f;
}
__device__ __forceinline__ float f_lo(unsigned u) {
    union { unsigned u; float f; } c; c.u = u << 16;
    return c.f;
}
__device__ __forceinline__ float f_hi(unsigned u) {
    union { unsigned u; float f; } c; c.u = u & 0xffff0000u;
    return c.f;
}
__device__ __forceinline__ unsigned pack4_fp8(float a, float b, float c, float d) {
    int r = __builtin_amdgcn_cvt_pk_fp8_f32(a, b, 0, false);
    r = __builtin_amdgcn_cvt_pk_fp8_f32(c, d, r, true);
    return (unsigned)r;
}

// decoder chain-graph degree
__device__ __forceinline__ float dinvdec(int p) {
    int d = (p >= 1) + (p >= 2) + (p <= NPG - 2) + (p <= NPG - 3);
    return rsqrtf((float)(d + 1));
}

// ---------------- CSR build (LDS-binned, no cross-XCD line sharing) ----------------

__global__ void zero_int_kernel(int* __restrict__ p, int n) {
    int i = blockIdx.x * 256 + threadIdx.x;
    if (i < n) p[i] = 0;
}

__global__ __launch_bounds__(256) void bin1_kernel(const int* __restrict__ src,
                                                   const int* __restrict__ dst,
                                                   int* __restrict__ gcur,
                                                   int* __restrict__ stage,
                                                   int E, int nbin) {
    __shared__ int bins[256][CAP];
    __shared__ int bcnt[256];
    const int tid = threadIdx.x;
    bcnt[tid] = 0;
    __syncthreads();

    const int e0 = blockIdx.x * TILE;
    const int cnt = min(TILE, E - e0);
    for (int i = tid; i < cnt; i += 256) {
        int s = src[e0 + i], d = dst[e0 + i];
        int b = d >> CSHIFT;
        int v = (s << CSHIFT) | (d & CMASK);
        int pos = atomicAdd(&bcnt[b], 1);
        if (pos < CAP) {
            bins[b][pos] = v;
        } else {  // rare spill: private 4-slot chunk, -1 pads
            int g = atomicAdd(&gcur[b * 16], 4);
            int* sp = stage + (size_t)b * SLOT + g;
            sp[0] = v; sp[1] = -1; sp[2] = -1; sp[3] = -1;
        }
    }
    __syncthreads();

    if (tid < nbin) {
        int c = min(bcnt[tid], CAP);
        int r = (c + 3) & ~3;
        if (r > 0) {
            int base = atomicAdd(&gcur[tid * 16], r);
            int* dstp = stage + (size_t)tid * SLOT + base;
            for (int j = 0; j < r; j += 4) {
                int4 v;
                v.x = (j + 0 < c) ? bins[tid][j + 0] : -1;
                v.y = (j + 1 < c) ? bins[tid][j + 1] : -1;
                v.z = (j + 2 < c) ? bins[tid][j + 2] : -1;
                v.w = (j + 3 < c) ? bins[tid][j + 3] : -1;
                *(int4*)(dstp + j) = v;
            }
        }
    }
}

__global__ __launch_bounds__(256) void bin_count_kernel(const int* __restrict__ gcur,
                                                        const int* __restrict__ stage,
                                                        int* __restrict__ cntg,
                                                        float* __restrict__ dinvg, int N) {
    __shared__ int lc[1 << CSHIFT];
    const int b = blockIdx.x;
    for (int j = threadIdx.x; j < (1 << CSHIFT); j += 256) lc[j] = 0;
    __syncthreads();
    const int len = gcur[b * 16];
    const int* sp = stage + (size_t)b * SLOT;
    for (int i = threadIdx.x; i < len; i += 256) {
        int v = sp[i];
        if (v >= 0) atomicAdd(&lc[v & CMASK], 1);
    }
    __syncthreads();
    const int d0 = b << CSHIFT;
    for (int j = threadIdx.x; j < (1 << CSHIFT); j += 256) {
        int d = d0 + j;
        if (d < N) {
            int c = lc[j];
            cntg[d] = c;
            dinvg[d] = rsqrtf((float)c + 1.0f);
        }
    }
}

__global__ __launch_bounds__(256) void scan1_kernel(const int* __restrict__ cnt,
                                                    int* __restrict__ row_ptr,
                                                    int* __restrict__ partials, int N) {
    __shared__ int sd[256];
    int tid = threadIdx.x;
    int base = blockIdx.x * 2048 + tid * 8;
    int v[8];
    int s = 0;
#pragma unroll
    for (int j = 0; j < 8; j++) {
        int i = base + j;
        int t = (i < N) ? cnt[i] : 0;
        v[j] = t; s += t;
    }
    sd[tid] = s;
    __syncthreads();
    for (int off = 1; off < 256; off <<= 1) {
        int t = (tid >= off) ? sd[tid - off] : 0;
        __syncthreads();
        sd[tid] += t;
        __syncthreads();
    }
    int run = sd[tid] - s;  // exclusive within block
#pragma unroll
    for (int j = 0; j < 8; j++) {
        int i = base + j;
        if (i < N) row_ptr[i] = run;
        run += v[j];
    }
    if (tid == 0) partials[blockIdx.x] = sd[255];
}

__global__ void scan2_kernel(int* __restrict__ partials, int nb) {
    __shared__ int sd[128];
    int tid = threadIdx.x;
    int v = (tid < nb) ? partials[tid] : 0;
    sd[tid] = v;
    __syncthreads();
    for (int off = 1; off < 128; off <<= 1) {
        int t = (tid >= off) ? sd[tid - off] : 0;
        __syncthreads();
        sd[tid] += t;
        __syncthreads();
    }
    if (tid < nb) partials[tid] = sd[tid] - v;
}

__global__ void scan3_kernel(int* __restrict__ row_ptr, const int* __restrict__ partials,
                             int N, int E) {
    int base = blockIdx.x * 2048 + threadIdx.x * 8;
    int add = partials[blockIdx.x];
#pragma unroll
    for (int j = 0; j < 8; j++) {
        int i = base + j;
        if (i < N) row_ptr[i] += add;
    }
    if (blockIdx.x == 0 && threadIdx.x == 0) row_ptr[N] = E;
}

__global__ __launch_bounds__(256) void bin_fill_kernel(const int* __restrict__ gcur,
                                                       const int* __restrict__ stage,
                                                       const int* __restrict__ row_ptr,
                                                       int* __restrict__ csr_src, int N) {
    __shared__ int cur[1 << CSHIFT];
    __shared__ int rp[1 << CSHIFT];
    const int b = blockIdx.x;
    const int d0 = b << CSHIFT;
    for (int j = threadIdx.x; j < (1 << CSHIFT); j += 256) {
        cur[j] = 0;
        int d = d0 + j;
        rp[j] = (d < N) ? row_ptr[d] : 0;
    }
    __syncthreads();
    const int len = gcur[b * 16];
    const int* sp = stage + (size_t)b * SLOT;
    for (int i = threadIdx.x; i < len; i += 256) {
        int v = sp[i];
        if (v >= 0) {
            int dl = v & CMASK;
            int pos = rp[dl] + atomicAdd(&cur[dl], 1);
            csr_src[pos] = v >> CSHIFT;
        }
    }
}

// ---------------- MFMA GEMM ----------------
// AMODE: 0 = fp32 A direct; 1 = packed bf16 A direct;
//        2 = closed-form decoder z1 (A = tbuf [NG][64], apre = b1);
//        3 = stencil over fp32 g; 4 = stencil over bf16 g;
//        5 = packed fp8 e4m3 A (decode in-reg).
// WP: 1 = plain bf16 W (1 MFMA), 2 = hi/lo split W+A (3 MFMA, fp32-grade).
// OMODE: 0 = fp32 out, 1 = packed bf16 out, 2 = packed fp8 e4m3 out.
template <int K, int N, int SCALE_MODE, bool BIAS, int AMODE, int WP, int OMODE>
__global__ __launch_bounds__(256, 2) void mfma_gemm(const float* __restrict__ A,
                                                    const float* __restrict__ W,
                                                    const float* __restrict__ bias,
                                                    const float* __restrict__ rowscale,
                                                    const float* __restrict__ apre,
                                                    float* __restrict__ out, int M) {
    constexpr int KP = K + 8;
    constexpr int NT = N / 16;
    constexpr int KS = K / 32;
    __shared__ unsigned short Wt[WP][N][KP];
    const int tid = threadIdx.x;

    for (int idx = tid; idx < K * N; idx += 256) {
        float w = W[idx];
        int k = idx / N, n = idx % N;  // N is pow2
        unsigned short h = bf16_rn(w);
        Wt[0][n][k] = h;
        if (WP == 2) Wt[1][n][k] = bf16_rn(w - bf16_f(h));
    }
    __syncthreads();

    const int lane = tid & 63;
    const int l15 = lane & 15;
    const int lg = lane >> 4;  // 0..3
    const int nstrips = M / 16;
    const int wglobal = blockIdx.x * 4 + (tid >> 6);
    const int wtotal = gridDim.x * 4;

    float curf[AMODE != 1 ? KS * 8 : 1], nxtf[AMODE != 1 ? KS * 8 : 1];
    uint4 curv[AMODE == 1 ? KS : 1], nxtv[AMODE == 1 ? KS : 1];

    // pre-bias (A-construction bias) for modes 2/3/4 — constant across strips
    float preb[(AMODE >= 2 && AMODE <= 4) ? KS * 8 : 1];
    if (AMODE >= 2 && AMODE <= 4) {
#pragma unroll
        for (int ks = 0; ks < KS; ks++)
#pragma unroll
            for (int j = 0; j < 8; j++) preb[ks * 8 + j] = apre[ks * 32 + lg * 8 + j];
    }

    auto loadA_f = [&](int s, float* dstv) {
        const float* arow = A + (size_t)(s * 16 + l15) * K + lg * 8;
#pragma unroll
        for (int ks = 0; ks < KS; ks++) {
            float4 a = *(const float4*)(arow + ks * 32);
            float4 b = *(const float4*)(arow + ks * 32 + 4);
            dstv[ks * 8 + 0] = a.x; dstv[ks * 8 + 1] = a.y;
            dstv[ks * 8 + 2] = a.z; dstv[ks * 8 + 3] = a.w;
            dstv[ks * 8 + 4] = b.x; dstv[ks * 8 + 5] = b.y;
            dstv[ks * 8 + 6] = b.z; dstv[ks * 8 + 7] = b.w;
        }
    };
    auto loadA_h = [&](int s, uint4* dstv) {
        const unsigned short* arow = (const unsigned short*)A + (size_t)(s * 16 + l15) * K + lg * 8;
#pragma unroll
        for (int ks = 0; ks < KS; ks++)
            dstv[ks] = *(const uint4*)(arow + ks * 32);
    };
    // mode 5: packed fp8 A -> decode to fp32
    auto loadA_f8 = [&](int s, float* dstv) {
        const unsigned char* arow = (const unsigned char*)A + (size_t)(s * 16 + l15) * K + lg * 8;
#pragma unroll
        for (int ks = 0; ks < KS; ks++) {
            uint2 v = *(const uint2*)(arow + ks * 32);
            f32x2 a0 = __builtin_amdgcn_cvt_pk_f32_fp8((int)v.x, false);
            f32x2 a1 = __builtin_amdgcn_cvt_pk_f32_fp8((int)v.x, true);
            f32x2 a2 = __builtin_amdgcn_cvt_pk_f32_fp8((int)v.y, false);
            f32x2 a3 = __builtin_amdgcn_cvt_pk_f32_fp8((int)v.y, true);
            dstv[ks * 8 + 0] = a0[0]; dstv[ks * 8 + 1] = a0[1];
            dstv[ks * 8 + 2] = a1[0]; dstv[ks * 8 + 3] = a1[1];
            dstv[ks * 8 + 4] = a2[0]; dstv[ks * 8 + 5] = a2[1];
            dstv[ks * 8 + 6] = a3[0]; dstv[ks * 8 + 7] = a3[1];
        }
    };
    // mode 2: z1 closed form from tbuf
    auto loadA_z1 = [&](int s, float* dstv) {
        int grow = s * 16 + l15;
        int gph = grow / NPG;
        int p = grow - gph * NPG;
        float dp = dinvdec(p);
        float qs = dp;
        if (p >= 1) qs += dinvdec(p - 1);
        if (p >= 2) qs += dinvdec(p - 2);
        if (p <= NPG - 2) qs += dinvdec(p + 1);
        if (p <= NPG - 3) qs += dinvdec(p + 2);
        float sc = dp * qs;
#pragma unroll
        for (int ks = 0; ks < KS; ks++) {
            const float* tr = A + gph * HID + ks * 32 + lg * 8;
            float4 a = *(const float4*)tr;
            float4 b = *(const float4*)(tr + 4);
            float av[8] = {a.x, a.y, a.z, a.w, b.x, b.y, b.z, b.w};
#pragma unroll
            for (int j = 0; j < 8; j++)
                dstv[ks * 8 + j] = fmaxf(sc * av[j] + preb[ks * 8 + j], 0.f);
        }
    };
    // modes 3/4: 5-point stencil over g (fp32 or bf16) + bias + relu
    auto loadA_st = [&](int s, float* dstv) {
        int grow = s * 16 + l15;
        int gph = grow / NPG;
        int p = grow - gph * NPG;
        float dd = dinvdec(p);
#pragma unroll
        for (int ks = 0; ks < KS; ks++) {
            float acc8[8] = {0.f, 0.f, 0.f, 0.f, 0.f, 0.f, 0.f, 0.f};
            const int cb = ks * 32 + lg * 8;
            if (AMODE == 3) {
                const float* base = A + (size_t)grow * K + cb;
                auto addr = [&](const float* rp) {
                    float4 a = *(const float4*)rp;
                    float4 b = *(const float4*)(rp + 4);
                    acc8[0] += a.x; acc8[1] += a.y; acc8[2] += a.z; acc8[3] += a.w;
                    acc8[4] += b.x; acc8[5] += b.y; acc8[6] += b.z; acc8[7] += b.w;
                };
                addr(base);
                if (p >= 1) addr(base - K);
                if (p >= 2) addr(base - 2 * K);
                if (p <= NPG - 2) addr(base + K);
                if (p <= NPG - 3) addr(base + 2 * K);
            } else {
                const unsigned short* base = (const unsigned short*)A + (size_t)grow * K + cb;
                auto addr = [&](const unsigned short* rp) {
                    uint4 v = *(const uint4*)rp;
                    acc8[0] += f_lo(v.x); acc8[1] += f_hi(v.x);
                    acc8[2] += f_lo(v.y); acc8[3] += f_hi(v.y);
                    acc8[4] += f_lo(v.z); acc8[5] += f_hi(v.z);
                    acc8[6] += f_lo(v.w); acc8[7] += f_hi(v.w);
                };
                addr(base);
                if (p >= 1) addr(base - K);
                if (p >= 2) addr(base - 2 * K);
                if (p <= NPG - 2) addr(base + K);
                if (p <= NPG - 3) addr(base + 2 * K);
            }
#pragma unroll
            for (int j = 0; j < 8; j++)
                dstv[ks * 8 + j] = fmaxf(dd * acc8[j] + preb[ks * 8 + j], 0.f);
        }
    };

    auto loadA = [&](int s) {
        if (AMODE == 0) loadA_f(s, nxtf);
        else if (AMODE == 1) loadA_h(s, nxtv);
        else if (AMODE == 2) loadA_z1(s, nxtf);
        else if (AMODE == 5) loadA_f8(s, nxtf);
        else loadA_st(s, nxtf);
    };

    int s = wglobal;
    if (s < nstrips) {
        loadA(s);
        if (AMODE == 1) { for (int i = 0; i < KS; i++) curv[i] = nxtv[i]; }
        else            { for (int i = 0; i < KS * 8; i++) curf[i] = nxtf[i]; }
    }
    for (; s < nstrips; s += wtotal) {
        int sn = s + wtotal;
        if (sn < nstrips) loadA(sn);

        f32x4 acc[NT];
#pragma unroll
        for (int t = 0; t < NT; t++) acc[t] = f32x4{0.f, 0.f, 0.f, 0.f};

#pragma unroll
        for (int ks = 0; ks < KS; ks++) {
            bf16x8 ah, al;
            if (AMODE == 1) {
                ah = *(bf16x8*)&curv[ks];
            } else {
#pragma unroll
                for (int j = 0; j < 8; j++) {
                    float v = curf[ks * 8 + j];
                    unsigned short h = bf16_rn(v);
                    ah[j] = (short)h;
                    if (WP == 2) al[j] = (short)bf16_rn(v - bf16_f(h));
                }
            }
            const int k0 = ks * 32 + lg * 8;
#pragma unroll
            for (int t = 0; t < NT; t++) {
                int n = t * 16 + l15;
                bf16x8 bh = *(const bf16x8*)&Wt[0][n][k0];
                acc[t] = __builtin_amdgcn_mfma_f32_16x16x32_bf16(ah, bh, acc[t], 0, 0, 0);
                if (WP == 2) {
                    bf16x8 bl = *(const bf16x8*)&Wt[1][n][k0];
                    acc[t] = __builtin_amdgcn_mfma_f32_16x16x32_bf16(ah, bl, acc[t], 0, 0, 0);
                    acc[t] = __builtin_amdgcn_mfma_f32_16x16x32_bf16(al, bh, acc[t], 0, 0, 0);
                }
            }
        }

#pragma unroll
        for (int r = 0; r < 4; r++) {
            int row = s * 16 + lg * 4 + r;
            float scale = 1.0f;
            if (SCALE_MODE == 1) scale = rowscale[row];
            if (SCALE_MODE == 2) scale = dinvdec(row % NPG);
#pragma unroll
            for (int t = 0; t < NT; t++) {
                float o = acc[t][r] * scale;
                if (BIAS) o += bias[t * 16 + l15];
                if (OMODE == 2) {
                    int p = __builtin_amdgcn_cvt_pk_fp8_f32(o, 0.0f, 0, false);
                    ((unsigned char*)out)[(size_t)row * N + t * 16 + l15] = (unsigned char)(p & 0xff);
                } else if (OMODE == 1) {
                    ((unsigned short*)out)[(size_t)row * N + t * 16 + l15] = bf16_rn(o);
                } else {
                    out[(size_t)row * N + t * 16 + l15] = o;
                }
            }
        }
        if (AMODE == 1) {
#pragma unroll
            for (int i = 0; i < KS; i++) curv[i] = nxtv[i];
        } else {
#pragma unroll
            for (int i = 0; i < KS * 8; i++) curf[i] = nxtf[i];
        }
    }
}

// ---------------- encoder aggregation (gather over CSR, fp8 rows -> fp8 h) ----------------
// Barrier-free; 8 lanes/row (uint2 = 8 fp8/lane), 32 rows/block; 8-deep pipeline.
// Low VGPR (~48-56) -> high occupancy -> more outstanding gathers.
__global__ __launch_bounds__(256) void agg_f8_kernel(const unsigned int* __restrict__ g,
                                                     const int* __restrict__ row_ptr,
                                                     const int* __restrict__ csr_src,
                                                     const float* __restrict__ dinv,
                                                     const float* __restrict__ bias,
                                                     unsigned int* __restrict__ out,
                                                     int N, int do_relu) {
    const int tid = threadIdx.x;
    const int sub = tid >> 3;        // 0..31: row within block
    const int lg = tid & 7;          // 8B group (8 fp8 values)
    const int row = blockIdx.x * 32 + sub;
    if (row >= N) return;

    const uint2* g2 = (const uint2*)g;
    float acc[8] = {};

#define D4(u, i0) do { \
    f32x2 lo = __builtin_amdgcn_cvt_pk_f32_fp8((int)(u), false); \
    f32x2 hi = __builtin_amdgcn_cvt_pk_f32_fp8((int)(u), true); \
    acc[i0 + 0] += lo[0]; acc[i0 + 1] += lo[1]; \
    acc[i0 + 2] += hi[0]; acc[i0 + 3] += hi[1]; } while (0)
#define ACCV(vv) do { D4(vv.x, 0); D4(vv.y, 4); } while (0)

    {   // self term
        uint2 v = g2[(size_t)row * 8 + lg];
        ACCV(v);
    }

    const int s = row_ptr[row];
    const int e = row_ptr[row + 1];
    int j = s;

    for (; j + 8 <= e; j += 8) {
        int idx[8];
#pragma unroll
        for (int t = 0; t < 8; t++) idx[t] = csr_src[j + t];
        uint2 v[8];
#pragma unroll
        for (int t = 0; t < 8; t++) v[t] = g2[(size_t)idx[t] * 8 + lg];
#pragma unroll
        for (int t = 0; t < 8; t++) ACCV(v[t]);
    }
    for (; j + 2 <= e; j += 2) {
        int i0 = csr_src[j + 0], i1 = csr_src[j + 1];
        uint2 v0 = g2[(size_t)i0 * 8 + lg];
        uint2 v1 = g2[(size_t)i1 * 8 + lg];
        ACCV(v0); ACCV(v1);
    }
    if (j < e) {
        uint2 v = g2[(size_t)csr_src[j] * 8 + lg];
        ACCV(v);
    }
#undef ACCV
#undef D4

    const float d = dinv[row];
    float h[8];
#pragma unroll
    for (int i = 0; i < 8; i++) {
        float a = d * acc[i] + bias[lg * 8 + i];
        if (do_relu) a = fmaxf(a, 0.0f);
        h[i] = a;
    }
    uint2 o;
    o.x = pack4_fp8(h[0], h[1], h[2], h[3]);
    o.y = pack4_fp8(h[4], h[5], h[6], h[7]);
    ((uint2*)out)[(size_t)row * 8 + lg] = o;
}

// ---------------- fused final agg + mean-pool ----------------
// 8 lanes/row, 32 rows/block (spans <=2 graphs). h never hits global; column
// partials atomicAdd into pre-zeroed fp32 emb. decinit applies /NPG.
__global__ __launch_bounds__(256) void agg_pool_kernel(const unsigned int* __restrict__ g,
                                                       const int* __restrict__ row_ptr,
                                                       const int* __restrict__ csr_src,
                                                       const float* __restrict__ dinv,
                                                       const float* __restrict__ bias,
                                                       float* __restrict__ emb, int N) {
    __shared__ float hs[32][68];
    const int tid = threadIdx.x;
    const int sub = tid >> 3;
    const int lg = tid & 7;
    const int row = blockIdx.x * 32 + sub;

    const uint2* g2 = (const uint2*)g;
    float acc[8] = {};

#define D4c(u, i0) do { \
    f32x2 lo = __builtin_amdgcn_cvt_pk_f32_fp8((int)(u), false); \
    f32x2 hi = __builtin_amdgcn_cvt_pk_f32_fp8((int)(u), true); \
    acc[i0 + 0] += lo[0]; acc[i0 + 1] += lo[1]; \
    acc[i0 + 2] += hi[0]; acc[i0 + 3] += hi[1]; } while (0)
#define ACCVc(vv) do { D4c(vv.x, 0); D4c(vv.y, 4); } while (0)

    {
        uint2 v = g2[(size_t)row * 8 + lg];
        ACCVc(v);
    }
    const int s = row_ptr[row];
    const int e = row_ptr[row + 1];
    int j = s;
    for (; j + 8 <= e; j += 8) {
        int idx[8];
#pragma unroll
        for (int t = 0; t < 8; t++) idx[t] = csr_src[j + t];
        uint2 v[8];
#pragma unroll
        for (int t = 0; t < 8; t++) v[t] = g2[(size_t)idx[t] * 8 + lg];
#pragma unroll
        for (int t = 0; t < 8; t++) ACCVc(v[t]);
    }
    for (; j + 2 <= e; j += 2) {
        int i0 = csr_src[j + 0], i1 = csr_src[j + 1];
        uint2 v0 = g2[(size_t)i0 * 8 + lg];
        uint2 v1 = g2[(size_t)i1 * 8 + lg];
        ACCVc(v0); ACCVc(v1);
    }
    if (j < e) {
        uint2 v = g2[(size_t)csr_src[j] * 8 + lg];
        ACCVc(v);
    }
#undef ACCVc
#undef D4c

    {   // h = d*acc + b (no relu, last encoder layer) -> LDS fp32
        const float d = dinv[row];
        float* hrow = &hs[sub][lg * 8];
#pragma unroll
        for (int i = 0; i < 8; i++)
            hrow[i] = d * acc[i] + bias[lg * 8 + i];
    }
    __syncthreads();

    if (tid < 64) {
        const int r0 = blockIdx.x * 32;
        const int g0 = r0 / NPG;
        int bnd = (g0 + 1) * NPG - r0;
        if (bnd > 32) bnd = 32;
        float sA = 0.f, sB = 0.f;
        for (int r = 0; r < 32; r++) {
            float v = hs[r][tid];
            if (r < bnd) sA += v; else sB += v;
        }
        atomicAdd(&emb[g0 * HID + tid], sA);
        if (bnd < 32) atomicAdd(&emb[(g0 + 1) * HID + tid], sB);
    }
}

// ---------------- decoder init: t = (emb/NPG @ Wt + bt) @ W1, one wave per graph ----------------
__global__ void decinit_kernel(const float* __restrict__ emb, const float* __restrict__ Wt,
                               const float* __restrict__ bt, const float* __restrict__ W1,
                               float* __restrict__ t, int NG) {
    int wid = (blockIdx.x * 256 + threadIdx.x) >> 6;
    int lane = threadIdx.x & 63;
    if (wid >= NG) return;
    float e = emb[wid * HID + lane] * (1.0f / NPG);
    float acc = bt[lane];
    for (int k = 0; k < HID; k++) acc += __shfl(e, k) * Wt[k * HID + lane];
    float tv = 0.0f;
    for (int k = 0; k < HID; k++) tv += __shfl(acc, k) * W1[k * HID + lane];
    t[wid * HID + lane] = tv;
}

// ---------------- launch ----------------

extern "C" void kernel_launch(void* const* d_in, const int* in_sizes, int n_in,
                              void* d_out, int out_size, void* d_ws, size_t ws_size,
                              hipStream_t stream) {
    const float* x      = (const float*)d_in[0];
    const int*   edge   = (const int*)d_in[1];
    const float* enc_W1 = (const float*)d_in[3];
    const float* enc_b1 = (const float*)d_in[4];
    const float* enc_W2 = (const float*)d_in[5];
    const float* enc_b2 = (const float*)d_in[6];
    const float* enc_W3 = (const float*)d_in[7];
    const float* enc_b3 = (const float*)d_in[8];
    const float* dec_Wt = (const float*)d_in[9];
    const float* dec_bt = (const float*)d_in[10];
    const float* dec_W1 = (const float*)d_in[11];
    const float* dec_b1 = (const float*)d_in[12];
    const float* dec_W2 = (const float*)d_in[13];
    const float* dec_b2 = (const float*)d_in[14];
    const float* dec_W3 = (const float*)d_in[15];
    const float* dec_b3 = (const float*)d_in[16];
    const float* out_W  = (const float*)d_in[17];
    const float* out_b  = (const float*)d_in[18];

    const int N  = in_sizes[0] / 128;  // 200000
    const int E  = in_sizes[1] / 2;    // 3200000
    const int NG = N / NPG;            // 2000
    const int NBIN = (N + CMASK) >> CSHIFT;  // 196
    const int* esrc = edge;
    const int* edst = edge + E;

    char* w = (char*)d_ws;
    auto alloc = [&](size_t bytes) -> void* {
        void* p = (void*)w;
        w += (bytes + 255) & ~(size_t)255;
        return p;
    };
    float* bufA    = (float*)alloc((size_t)N * HID * 4);   // fp8 g_a/g_b (encoder) / bf16 g2 (decoder)
    int*   csr     = (int*)alloc((size_t)E * 4);
    int*   row_ptr = (int*)alloc((size_t)(N + 1) * 4);
    int*   cnt     = (int*)alloc((size_t)N * 4);
    float* dinv    = (float*)alloc((size_t)N * 4);
    int*   partials= (int*)alloc(1024);
    float* emb     = (float*)alloc((size_t)NG * HID * 4);
    float* tbuf    = (float*)alloc((size_t)NG * HID * 4);
    int*   gcur    = (int*)alloc((size_t)NBIN * 16 * 4);
    int*   stage   = (int*)alloc((size_t)NBIN * SLOT * 4);  // 25.69 MB; reused as g3 (bf16)

    unsigned char* g_a = (unsigned char*)bufA;                       // 12.8 MB fp8
    unsigned char* g_b = (unsigned char*)bufA + (size_t)N * HID;     // 12.8 MB fp8
    unsigned short* g3 = (unsigned short*)stage;  // CSR staging dead after encoder

    const int NB = (N + 2047) / 2048;
    const int GB = 1024;  // gemm blocks (4 waves each)

    // CSR build: LDS-binned two-phase, no random global atomics
    zero_int_kernel<<<(NBIN * 16 + 255) / 256, 256, 0, stream>>>(gcur, NBIN * 16);
    bin1_kernel<<<(E + TILE - 1) / TILE, 256, 0, stream>>>(esrc, edst, gcur, stage, E, NBIN);
    bin_count_kernel<<<NBIN, 256, 0, stream>>>(gcur, stage, cnt, dinv, N);
    scan1_kernel<<<NB, 256, 0, stream>>>(cnt, row_ptr, partials, N);
    scan2_kernel<<<1, 128, 0, stream>>>(partials, NB);
    scan3_kernel<<<NB, 256, 0, stream>>>(row_ptr, partials, N, E);
    bin_fill_kernel<<<NBIN, 256, 0, stream>>>(gcur, stage, row_ptr, csr, N);

    // encoder: gemm1 -> g_a; {agg (fp8 h) + small fp8-A gemm} x2; fused final agg+pool -> emb
    zero_int_kernel<<<(NG * HID + 255) / 256, 256, 0, stream>>>((int*)emb, NG * HID);
    mfma_gemm<128, 64, 1, false, 0, 1, 2><<<GB, 256, 0, stream>>>(x, enc_W1, nullptr, dinv, nullptr,
                                                                  (float*)g_a, N);
    agg_f8_kernel<<<N / 32, 256, 0, stream>>>((const unsigned*)g_a, row_ptr, csr, dinv, enc_b1,
                                              (unsigned*)g_b, N, 1);
    mfma_gemm<64, 64, 1, false, 5, 1, 2><<<GB, 256, 0, stream>>>((const float*)g_b, enc_W2, nullptr,
                                                                 dinv, nullptr, (float*)g_a, N);
    agg_f8_kernel<<<N / 32, 256, 0, stream>>>((const unsigned*)g_a, row_ptr, csr, dinv, enc_b2,
                                              (unsigned*)g_b, N, 1);
    mfma_gemm<64, 64, 1, false, 5, 1, 2><<<GB, 256, 0, stream>>>((const float*)g_b, enc_W3, nullptr,
                                                                 dinv, nullptr, (float*)g_a, N);
    agg_pool_kernel<<<N / 32, 256, 0, stream>>>((const unsigned*)g_a, row_ptr, csr, dinv, enc_b3,
                                                emb, N);

    // decoder head
    decinit_kernel<<<(NG * 64 + 255) / 256, 256, 0, stream>>>(emb, dec_Wt, dec_bt, dec_W1, tbuf, NG);

    // decoder as 3 GEMMs with fused A-construction (bf16 intermediates):
    mfma_gemm<64, 64, 2, false, 2, 2, 1><<<GB, 256, 0, stream>>>(tbuf, dec_W2, nullptr, nullptr,
                                                                 dec_b1, bufA, N);
    mfma_gemm<64, 64, 2, false, 4, 2, 1><<<GB, 256, 0, stream>>>(bufA, dec_W3, nullptr, nullptr,
                                                                 dec_b2, (float*)g3, N);
    mfma_gemm<64, 128, 0, true, 4, 2, 0><<<GB, 256, 0, stream>>>((const float*)g3, out_W, out_b, nullptr,
                                                                 dec_b3, (float*)d_out, N);
}

// Round 15
// 408.072 us; speedup vs baseline: 1.0713x; 1.0034x over previous
//
#include <hip/hip_runtime.h>
#include <hip/hip_bf16.h>
#include <cstdint>

#define HID 64
#define NPG 100

// coarse buckets for CSR build: 1024 dsts per bucket
#define CSHIFT 10
#define CMASK ((1 << CSHIFT) - 1)
#define CAP 56          // LDS slots per bin per tile (λ≈42, spill ~1%)
#define TILE 8192       // edges per phase-1 block
#define SLOT 32768      // staging ints per bucket (mean ~16.6k, 2x slack)

typedef short bf16x8 __attribute__((ext_vector_type(8)));
typedef float f32x4 __attribute__((ext_vector_type(4)));
typedef float f32x2 __attribute__((ext_vector_type(2)));

__device__ __forceinline__ unsigned short bf16_rn(float f) {
    union { float f; unsigned u; } c; c.f = f;
    unsigned r = c.u + 0x7fffu + ((c.u >> 16) & 1u);
    return (unsigned short)(r >> 16);
}
__device__ __forceinline__ float bf16_f(unsigned short h) {
    union { unsigned u; float f; } c; c.u = ((unsigned)h) << 16;
    return c.f;
}
__device__ __forceinline__ float f_lo(unsigned u) {
    union { unsigned u; float f; } c; c.u = u << 16;
    return c.f;
}
__device__ __forceinline__ float f_hi(unsigned u) {
    union { unsigned u; float f; } c; c.u = u & 0xffff0000u;
    return c.f;
}
__device__ __forceinline__ unsigned pack4_fp8(float a, float b, float c, float d) {
    int r = __builtin_amdgcn_cvt_pk_fp8_f32(a, b, 0, false);
    r = __builtin_amdgcn_cvt_pk_fp8_f32(c, d, r, true);
    return (unsigned)r;
}

// decoder chain-graph degree
__device__ __forceinline__ float dinvdec(int p) {
    int d = (p >= 1) + (p >= 2) + (p <= NPG - 2) + (p <= NPG - 3);
    return rsqrtf((float)(d + 1));
}

// ---------------- CSR build (LDS-binned, no cross-XCD line sharing) ----------------

__global__ void zero_int_kernel(int* __restrict__ p, int n) {
    int i = blockIdx.x * 256 + threadIdx.x;
    if (i < n) p[i] = 0;
}

__global__ __launch_bounds__(256) void bin1_kernel(const int* __restrict__ src,
                                                   const int* __restrict__ dst,
                                                   int* __restrict__ gcur,
                                                   int* __restrict__ stage,
                                                   int E, int nbin) {
    __shared__ int bins[256][CAP];
    __shared__ int bcnt[256];
    const int tid = threadIdx.x;
    bcnt[tid] = 0;
    __syncthreads();

    const int e0 = blockIdx.x * TILE;
    const int cnt = min(TILE, E - e0);
    for (int i = tid; i < cnt; i += 256) {
        int s = src[e0 + i], d = dst[e0 + i];
        int b = d >> CSHIFT;
        int v = (s << CSHIFT) | (d & CMASK);
        int pos = atomicAdd(&bcnt[b], 1);
        if (pos < CAP) {
            bins[b][pos] = v;
        } else {  // rare spill: private 4-slot chunk, -1 pads
            int g = atomicAdd(&gcur[b * 16], 4);
            int* sp = stage + (size_t)b * SLOT + g;
            sp[0] = v; sp[1] = -1; sp[2] = -1; sp[3] = -1;
        }
    }
    __syncthreads();

    if (tid < nbin) {
        int c = min(bcnt[tid], CAP);
        int r = (c + 3) & ~3;
        if (r > 0) {
            int base = atomicAdd(&gcur[tid * 16], r);
            int* dstp = stage + (size_t)tid * SLOT + base;
            for (int j = 0; j < r; j += 4) {
                int4 v;
                v.x = (j + 0 < c) ? bins[tid][j + 0] : -1;
                v.y = (j + 1 < c) ? bins[tid][j + 1] : -1;
                v.z = (j + 2 < c) ? bins[tid][j + 2] : -1;
                v.w = (j + 3 < c) ? bins[tid][j + 3] : -1;
                *(int4*)(dstp + j) = v;
            }
        }
    }
}

__global__ __launch_bounds__(256) void bin_count_kernel(const int* __restrict__ gcur,
                                                        const int* __restrict__ stage,
                                                        int* __restrict__ cntg,
                                                        float* __restrict__ dinvg, int N) {
    __shared__ int lc[1 << CSHIFT];
    const int b = blockIdx.x;
    for (int j = threadIdx.x; j < (1 << CSHIFT); j += 256) lc[j] = 0;
    __syncthreads();
    const int len = gcur[b * 16];
    const int* sp = stage + (size_t)b * SLOT;
    for (int i = threadIdx.x; i < len; i += 256) {
        int v = sp[i];
        if (v >= 0) atomicAdd(&lc[v & CMASK], 1);
    }
    __syncthreads();
    const int d0 = b << CSHIFT;
    for (int j = threadIdx.x; j < (1 << CSHIFT); j += 256) {
        int d = d0 + j;
        if (d < N) {
            int c = lc[j];
            cntg[d] = c;
            dinvg[d] = rsqrtf((float)c + 1.0f);
        }
    }
}

// scans PADDED counts (each row rounded up to multiple of 8)
__global__ __launch_bounds__(256) void scan1_kernel(const int* __restrict__ cnt,
                                                    int* __restrict__ row_ptr,
                                                    int* __restrict__ partials, int N) {
    __shared__ int sd[256];
    int tid = threadIdx.x;
    int base = blockIdx.x * 2048 + tid * 8;
    int v[8];
    int s = 0;
#pragma unroll
    for (int j = 0; j < 8; j++) {
        int i = base + j;
        int t = (i < N) ? ((cnt[i] + 7) & ~7) : 0;
        v[j] = t; s += t;
    }
    sd[tid] = s;
    __syncthreads();
    for (int off = 1; off < 256; off <<= 1) {
        int t = (tid >= off) ? sd[tid - off] : 0;
        __syncthreads();
        sd[tid] += t;
        __syncthreads();
    }
    int run = sd[tid] - s;  // exclusive within block
#pragma unroll
    for (int j = 0; j < 8; j++) {
        int i = base + j;
        if (i < N) row_ptr[i] = run;
        run += v[j];
    }
    if (tid == 0) partials[blockIdx.x] = sd[255];
}

__global__ void scan2_kernel(int* __restrict__ partials, int nb) {
    __shared__ int sd[128];
    int tid = threadIdx.x;
    int v = (tid < nb) ? partials[tid] : 0;
    sd[tid] = v;
    __syncthreads();
    for (int off = 1; off < 128; off <<= 1) {
        int t = (tid >= off) ? sd[tid - off] : 0;
        __syncthreads();
        sd[tid] += t;
        __syncthreads();
    }
    if (tid < nb) partials[tid] = sd[tid] - v;
}

__global__ void scan3_kernel(int* __restrict__ row_ptr, const int* __restrict__ partials,
                             const int* __restrict__ cnt, int N) {
    int base = blockIdx.x * 2048 + threadIdx.x * 8;
    int add = partials[blockIdx.x];
#pragma unroll
    for (int j = 0; j < 8; j++) {
        int i = base + j;
        if (i < N) {
            int rp = row_ptr[i] + add;
            row_ptr[i] = rp;
            if (i == N - 1) row_ptr[N] = rp + ((cnt[i] + 7) & ~7);
        }
    }
}

// fill the pad slots of each row with the dummy index N (points at zero row of g)
__global__ void pad_kernel(const int* __restrict__ row_ptr, const int* __restrict__ cnt,
                           int* __restrict__ csr_src, int N) {
    int i = blockIdx.x * 256 + threadIdx.x;
    if (i >= N) return;
    int st = row_ptr[i] + cnt[i];
    int en = row_ptr[i + 1];
    for (int k = st; k < en; k++) csr_src[k] = N;
}

// zero the dummy row (index N) of both fp8 g buffers (64 B each)
__global__ void zero_dummy_kernel(unsigned int* __restrict__ ga, unsigned int* __restrict__ gb, int N) {
    int t = threadIdx.x;
    if (t < 16) ga[(size_t)N * 16 + t] = 0;
    else if (t < 32) gb[(size_t)N * 16 + (t - 16)] = 0;
}

__global__ __launch_bounds__(256) void bin_fill_kernel(const int* __restrict__ gcur,
                                                       const int* __restrict__ stage,
                                                       const int* __restrict__ row_ptr,
                                                       int* __restrict__ csr_src, int N) {
    __shared__ int cur[1 << CSHIFT];
    __shared__ int rp[1 << CSHIFT];
    const int b = blockIdx.x;
    const int d0 = b << CSHIFT;
    for (int j = threadIdx.x; j < (1 << CSHIFT); j += 256) {
        cur[j] = 0;
        int d = d0 + j;
        rp[j] = (d < N) ? row_ptr[d] : 0;
    }
    __syncthreads();
    const int len = gcur[b * 16];
    const int* sp = stage + (size_t)b * SLOT;
    for (int i = threadIdx.x; i < len; i += 256) {
        int v = sp[i];
        if (v >= 0) {
            int dl = v & CMASK;
            int pos = rp[dl] + atomicAdd(&cur[dl], 1);
            csr_src[pos] = v >> CSHIFT;
        }
    }
}

// ---------------- MFMA GEMM ----------------
// AMODE: 0 = fp32 A direct; 1 = packed bf16 A direct;
//        2 = closed-form decoder z1 (A = tbuf [NG][64], apre = b1);
//        3 = stencil over fp32 g; 4 = stencil over bf16 g;
//        5 = packed fp8 e4m3 A (decode in-reg).
// WP: 1 = plain bf16 W (1 MFMA), 2 = hi/lo split W+A (3 MFMA, fp32-grade).
// OMODE: 0 = fp32 out, 1 = packed bf16 out, 2 = packed fp8 e4m3 out.
template <int K, int N, int SCALE_MODE, bool BIAS, int AMODE, int WP, int OMODE>
__global__ __launch_bounds__(256, 2) void mfma_gemm(const float* __restrict__ A,
                                                    const float* __restrict__ W,
                                                    const float* __restrict__ bias,
                                                    const float* __restrict__ rowscale,
                                                    const float* __restrict__ apre,
                                                    float* __restrict__ out, int M) {
    constexpr int KP = K + 8;
    constexpr int NT = N / 16;
    constexpr int KS = K / 32;
    __shared__ unsigned short Wt[WP][N][KP];
    const int tid = threadIdx.x;

    for (int idx = tid; idx < K * N; idx += 256) {
        float w = W[idx];
        int k = idx / N, n = idx % N;  // N is pow2
        unsigned short h = bf16_rn(w);
        Wt[0][n][k] = h;
        if (WP == 2) Wt[1][n][k] = bf16_rn(w - bf16_f(h));
    }
    __syncthreads();

    const int lane = tid & 63;
    const int l15 = lane & 15;
    const int lg = lane >> 4;  // 0..3
    const int nstrips = M / 16;
    const int wglobal = blockIdx.x * 4 + (tid >> 6);
    const int wtotal = gridDim.x * 4;

    float curf[AMODE != 1 ? KS * 8 : 1], nxtf[AMODE != 1 ? KS * 8 : 1];
    uint4 curv[AMODE == 1 ? KS : 1], nxtv[AMODE == 1 ? KS : 1];

    // pre-bias (A-construction bias) for modes 2/3/4 — constant across strips
    float preb[(AMODE >= 2 && AMODE <= 4) ? KS * 8 : 1];
    if (AMODE >= 2 && AMODE <= 4) {
#pragma unroll
        for (int ks = 0; ks < KS; ks++)
#pragma unroll
            for (int j = 0; j < 8; j++) preb[ks * 8 + j] = apre[ks * 32 + lg * 8 + j];
    }

    auto loadA_f = [&](int s, float* dstv) {
        const float* arow = A + (size_t)(s * 16 + l15) * K + lg * 8;
#pragma unroll
        for (int ks = 0; ks < KS; ks++) {
            float4 a = *(const float4*)(arow + ks * 32);
            float4 b = *(const float4*)(arow + ks * 32 + 4);
            dstv[ks * 8 + 0] = a.x; dstv[ks * 8 + 1] = a.y;
            dstv[ks * 8 + 2] = a.z; dstv[ks * 8 + 3] = a.w;
            dstv[ks * 8 + 4] = b.x; dstv[ks * 8 + 5] = b.y;
            dstv[ks * 8 + 6] = b.z; dstv[ks * 8 + 7] = b.w;
        }
    };
    auto loadA_h = [&](int s, uint4* dstv) {
        const unsigned short* arow = (const unsigned short*)A + (size_t)(s * 16 + l15) * K + lg * 8;
#pragma unroll
        for (int ks = 0; ks < KS; ks++)
            dstv[ks] = *(const uint4*)(arow + ks * 32);
    };
    // mode 5: packed fp8 A -> decode to fp32
    auto loadA_f8 = [&](int s, float* dstv) {
        const unsigned char* arow = (const unsigned char*)A + (size_t)(s * 16 + l15) * K + lg * 8;
#pragma unroll
        for (int ks = 0; ks < KS; ks++) {
            uint2 v = *(const uint2*)(arow + ks * 32);
            f32x2 a0 = __builtin_amdgcn_cvt_pk_f32_fp8((int)v.x, false);
            f32x2 a1 = __builtin_amdgcn_cvt_pk_f32_fp8((int)v.x, true);
            f32x2 a2 = __builtin_amdgcn_cvt_pk_f32_fp8((int)v.y, false);
            f32x2 a3 = __builtin_amdgcn_cvt_pk_f32_fp8((int)v.y, true);
            dstv[ks * 8 + 0] = a0[0]; dstv[ks * 8 + 1] = a0[1];
            dstv[ks * 8 + 2] = a1[0]; dstv[ks * 8 + 3] = a1[1];
            dstv[ks * 8 + 4] = a2[0]; dstv[ks * 8 + 5] = a2[1];
            dstv[ks * 8 + 6] = a3[0]; dstv[ks * 8 + 7] = a3[1];
        }
    };
    // mode 2: z1 closed form from tbuf
    auto loadA_z1 = [&](int s, float* dstv) {
        int grow = s * 16 + l15;
        int gph = grow / NPG;
        int p = grow - gph * NPG;
        float dp = dinvdec(p);
        float qs = dp;
        if (p >= 1) qs += dinvdec(p - 1);
        if (p >= 2) qs += dinvdec(p - 2);
        if (p <= NPG - 2) qs += dinvdec(p + 1);
        if (p <= NPG - 3) qs += dinvdec(p + 2);
        float sc = dp * qs;
#pragma unroll
        for (int ks = 0; ks < KS; ks++) {
            const float* tr = A + gph * HID + ks * 32 + lg * 8;
            float4 a = *(const float4*)tr;
            float4 b = *(const float4*)(tr + 4);
            float av[8] = {a.x, a.y, a.z, a.w, b.x, b.y, b.z, b.w};
#pragma unroll
            for (int j = 0; j < 8; j++)
                dstv[ks * 8 + j] = fmaxf(sc * av[j] + preb[ks * 8 + j], 0.f);
        }
    };
    // modes 3/4: 5-point stencil over g (fp32 or bf16) + bias + relu
    auto loadA_st = [&](int s, float* dstv) {
        int grow = s * 16 + l15;
        int gph = grow / NPG;
        int p = grow - gph * NPG;
        float dd = dinvdec(p);
#pragma unroll
        for (int ks = 0; ks < KS; ks++) {
            float acc8[8] = {0.f, 0.f, 0.f, 0.f, 0.f, 0.f, 0.f, 0.f};
            const int cb = ks * 32 + lg * 8;
            if (AMODE == 3) {
                const float* base = A + (size_t)grow * K + cb;
                auto addr = [&](const float* rp) {
                    float4 a = *(const float4*)rp;
                    float4 b = *(const float4*)(rp + 4);
                    acc8[0] += a.x; acc8[1] += a.y; acc8[2] += a.z; acc8[3] += a.w;
                    acc8[4] += b.x; acc8[5] += b.y; acc8[6] += b.z; acc8[7] += b.w;
                };
                addr(base);
                if (p >= 1) addr(base - K);
                if (p >= 2) addr(base - 2 * K);
                if (p <= NPG - 2) addr(base + K);
                if (p <= NPG - 3) addr(base + 2 * K);
            } else {
                const unsigned short* base = (const unsigned short*)A + (size_t)grow * K + cb;
                auto addr = [&](const unsigned short* rp) {
                    uint4 v = *(const uint4*)rp;
                    acc8[0] += f_lo(v.x); acc8[1] += f_hi(v.x);
                    acc8[2] += f_lo(v.y); acc8[3] += f_hi(v.y);
                    acc8[4] += f_lo(v.z); acc8[5] += f_hi(v.z);
                    acc8[6] += f_lo(v.w); acc8[7] += f_hi(v.w);
                };
                addr(base);
                if (p >= 1) addr(base - K);
                if (p >= 2) addr(base - 2 * K);
                if (p <= NPG - 2) addr(base + K);
                if (p <= NPG - 3) addr(base + 2 * K);
            }
#pragma unroll
            for (int j = 0; j < 8; j++)
                dstv[ks * 8 + j] = fmaxf(dd * acc8[j] + preb[ks * 8 + j], 0.f);
        }
    };

    auto loadA = [&](int s) {
        if (AMODE == 0) loadA_f(s, nxtf);
        else if (AMODE == 1) loadA_h(s, nxtv);
        else if (AMODE == 2) loadA_z1(s, nxtf);
        else if (AMODE == 5) loadA_f8(s, nxtf);
        else loadA_st(s, nxtf);
    };

    int s = wglobal;
    if (s < nstrips) {
        loadA(s);
        if (AMODE == 1) { for (int i = 0; i < KS; i++) curv[i] = nxtv[i]; }
        else            { for (int i = 0; i < KS * 8; i++) curf[i] = nxtf[i]; }
    }
    for (; s < nstrips; s += wtotal) {
        int sn = s + wtotal;
        if (sn < nstrips) loadA(sn);

        f32x4 acc[NT];
#pragma unroll
        for (int t = 0; t < NT; t++) acc[t] = f32x4{0.f, 0.f, 0.f, 0.f};

#pragma unroll
        for (int ks = 0; ks < KS; ks++) {
            bf16x8 ah, al;
            if (AMODE == 1) {
                ah = *(bf16x8*)&curv[ks];
            } else {
#pragma unroll
                for (int j = 0; j < 8; j++) {
                    float v = curf[ks * 8 + j];
                    unsigned short h = bf16_rn(v);
                    ah[j] = (short)h;
                    if (WP == 2) al[j] = (short)bf16_rn(v - bf16_f(h));
                }
            }
            const int k0 = ks * 32 + lg * 8;
#pragma unroll
            for (int t = 0; t < NT; t++) {
                int n = t * 16 + l15;
                bf16x8 bh = *(const bf16x8*)&Wt[0][n][k0];
                acc[t] = __builtin_amdgcn_mfma_f32_16x16x32_bf16(ah, bh, acc[t], 0, 0, 0);
                if (WP == 2) {
                    bf16x8 bl = *(const bf16x8*)&Wt[1][n][k0];
                    acc[t] = __builtin_amdgcn_mfma_f32_16x16x32_bf16(ah, bl, acc[t], 0, 0, 0);
                    acc[t] = __builtin_amdgcn_mfma_f32_16x16x32_bf16(al, bh, acc[t], 0, 0, 0);
                }
            }
        }

#pragma unroll
        for (int r = 0; r < 4; r++) {
            int row = s * 16 + lg * 4 + r;
            float scale = 1.0f;
            if (SCALE_MODE == 1) scale = rowscale[row];
            if (SCALE_MODE == 2) scale = dinvdec(row % NPG);
#pragma unroll
            for (int t = 0; t < NT; t++) {
                float o = acc[t][r] * scale;
                if (BIAS) o += bias[t * 16 + l15];
                if (OMODE == 2) {
                    int p = __builtin_amdgcn_cvt_pk_fp8_f32(o, 0.0f, 0, false);
                    ((unsigned char*)out)[(size_t)row * N + t * 16 + l15] = (unsigned char)(p & 0xff);
                } else if (OMODE == 1) {
                    ((unsigned short*)out)[(size_t)row * N + t * 16 + l15] = bf16_rn(o);
                } else {
                    out[(size_t)row * N + t * 16 + l15] = o;
                }
            }
        }
        if (AMODE == 1) {
#pragma unroll
            for (int i = 0; i < KS; i++) curv[i] = nxtv[i];
        } else {
#pragma unroll
            for (int i = 0; i < KS * 8; i++) curf[i] = nxtf[i];
        }
    }
}

// ---------------- encoder aggregation (gather over CSR, fp8 rows -> fp8 h) ----------------
// Padded CSR: every row's edge count is a multiple of 8 (dummies -> zero row N).
// Barrier-free; 8 lanes/row (uint2), 32 rows/block; uniform 8-deep pipeline, no tails.
__global__ __launch_bounds__(256) void agg_f8_kernel(const unsigned int* __restrict__ g,
                                                     const int* __restrict__ row_ptr,
                                                     const int* __restrict__ csr_src,
                                                     const float* __restrict__ dinv,
                                                     const float* __restrict__ bias,
                                                     unsigned int* __restrict__ out,
                                                     int N, int do_relu) {
    const int tid = threadIdx.x;
    const int sub = tid >> 3;        // 0..31: row within block
    const int lg = tid & 7;          // 8B group (8 fp8 values)
    const int row = blockIdx.x * 32 + sub;
    if (row >= N) return;

    const uint2* g2 = (const uint2*)g;
    float acc[8] = {};

#define D4(u, i0) do { \
    f32x2 lo = __builtin_amdgcn_cvt_pk_f32_fp8((int)(u), false); \
    f32x2 hi = __builtin_amdgcn_cvt_pk_f32_fp8((int)(u), true); \
    acc[i0 + 0] += lo[0]; acc[i0 + 1] += lo[1]; \
    acc[i0 + 2] += hi[0]; acc[i0 + 3] += hi[1]; } while (0)
#define ACCV(vv) do { D4(vv.x, 0); D4(vv.y, 4); } while (0)

    {   // self term
        uint2 v = g2[(size_t)row * 8 + lg];
        ACCV(v);
    }

    const int s = row_ptr[row];
    const int e = row_ptr[row + 1];
    for (int j = s; j < e; j += 8) {
        int idx[8];
#pragma unroll
        for (int t = 0; t < 8; t++) idx[t] = csr_src[j + t];
        uint2 v[8];
#pragma unroll
        for (int t = 0; t < 8; t++) v[t] = g2[(size_t)idx[t] * 8 + lg];
#pragma unroll
        for (int t = 0; t < 8; t++) ACCV(v[t]);
    }
#undef ACCV
#undef D4

    const float d = dinv[row];
    float h[8];
#pragma unroll
    for (int i = 0; i < 8; i++) {
        float a = d * acc[i] + bias[lg * 8 + i];
        if (do_relu) a = fmaxf(a, 0.0f);
        h[i] = a;
    }
    uint2 o;
    o.x = pack4_fp8(h[0], h[1], h[2], h[3]);
    o.y = pack4_fp8(h[4], h[5], h[6], h[7]);
    ((uint2*)out)[(size_t)row * 8 + lg] = o;
}

// ---------------- fused final agg + mean-pool ----------------
// Padded CSR, uniform batches. 8 lanes/row, 32 rows/block (spans <=2 graphs).
__global__ __launch_bounds__(256) void agg_pool_kernel(const unsigned int* __restrict__ g,
                                                       const int* __restrict__ row_ptr,
                                                       const int* __restrict__ csr_src,
                                                       const float* __restrict__ dinv,
                                                       const float* __restrict__ bias,
                                                       float* __restrict__ emb, int N) {
    __shared__ float hs[32][68];
    const int tid = threadIdx.x;
    const int sub = tid >> 3;
    const int lg = tid & 7;
    const int row = blockIdx.x * 32 + sub;

    const uint2* g2 = (const uint2*)g;
    float acc[8] = {};

#define D4c(u, i0) do { \
    f32x2 lo = __builtin_amdgcn_cvt_pk_f32_fp8((int)(u), false); \
    f32x2 hi = __builtin_amdgcn_cvt_pk_f32_fp8((int)(u), true); \
    acc[i0 + 0] += lo[0]; acc[i0 + 1] += lo[1]; \
    acc[i0 + 2] += hi[0]; acc[i0 + 3] += hi[1]; } while (0)
#define ACCVc(vv) do { D4c(vv.x, 0); D4c(vv.y, 4); } while (0)

    {
        uint2 v = g2[(size_t)row * 8 + lg];
        ACCVc(v);
    }
    const int s = row_ptr[row];
    const int e = row_ptr[row + 1];
    for (int j = s; j < e; j += 8) {
        int idx[8];
#pragma unroll
        for (int t = 0; t < 8; t++) idx[t] = csr_src[j + t];
        uint2 v[8];
#pragma unroll
        for (int t = 0; t < 8; t++) v[t] = g2[(size_t)idx[t] * 8 + lg];
#pragma unroll
        for (int t = 0; t < 8; t++) ACCVc(v[t]);
    }
#undef ACCVc
#undef D4c

    {   // h = d*acc + b (no relu, last encoder layer) -> LDS fp32
        const float d = dinv[row];
        float* hrow = &hs[sub][lg * 8];
#pragma unroll
        for (int i = 0; i < 8; i++)
            hrow[i] = d * acc[i] + bias[lg * 8 + i];
    }
    __syncthreads();

    if (tid < 64) {
        const int r0 = blockIdx.x * 32;
        const int g0 = r0 / NPG;
        int bnd = (g0 + 1) * NPG - r0;
        if (bnd > 32) bnd = 32;
        float sA = 0.f, sB = 0.f;
        for (int r = 0; r < 32; r++) {
            float v = hs[r][tid];
            if (r < bnd) sA += v; else sB += v;
        }
        atomicAdd(&emb[g0 * HID + tid], sA);
        if (bnd < 32) atomicAdd(&emb[(g0 + 1) * HID + tid], sB);
    }
}

// ---------------- decoder init: t = (emb/NPG @ Wt + bt) @ W1, one wave per graph ----------------
__global__ void decinit_kernel(const float* __restrict__ emb, const float* __restrict__ Wt,
                               const float* __restrict__ bt, const float* __restrict__ W1,
                               float* __restrict__ t, int NG) {
    int wid = (blockIdx.x * 256 + threadIdx.x) >> 6;
    int lane = threadIdx.x & 63;
    if (wid >= NG) return;
    float e = emb[wid * HID + lane] * (1.0f / NPG);
    float acc = bt[lane];
    for (int k = 0; k < HID; k++) acc += __shfl(e, k) * Wt[k * HID + lane];
    float tv = 0.0f;
    for (int k = 0; k < HID; k++) tv += __shfl(acc, k) * W1[k * HID + lane];
    t[wid * HID + lane] = tv;
}

// ---------------- launch ----------------

extern "C" void kernel_launch(void* const* d_in, const int* in_sizes, int n_in,
                              void* d_out, int out_size, void* d_ws, size_t ws_size,
                              hipStream_t stream) {
    const float* x      = (const float*)d_in[0];
    const int*   edge   = (const int*)d_in[1];
    const float* enc_W1 = (const float*)d_in[3];
    const float* enc_b1 = (const float*)d_in[4];
    const float* enc_W2 = (const float*)d_in[5];
    const float* enc_b2 = (const float*)d_in[6];
    const float* enc_W3 = (const float*)d_in[7];
    const float* enc_b3 = (const float*)d_in[8];
    const float* dec_Wt = (const float*)d_in[9];
    const float* dec_bt = (const float*)d_in[10];
    const float* dec_W1 = (const float*)d_in[11];
    const float* dec_b1 = (const float*)d_in[12];
    const float* dec_W2 = (const float*)d_in[13];
    const float* dec_b2 = (const float*)d_in[14];
    const float* dec_W3 = (const float*)d_in[15];
    const float* dec_b3 = (const float*)d_in[16];
    const float* out_W  = (const float*)d_in[17];
    const float* out_b  = (const float*)d_in[18];

    const int N  = in_sizes[0] / 128;  // 200000
    const int E  = in_sizes[1] / 2;    // 3200000
    const int NG = N / NPG;            // 2000
    const int NBIN = (N + CMASK) >> CSHIFT;  // 196
    const int* esrc = edge;
    const int* edst = edge + E;

    char* w = (char*)d_ws;
    auto alloc = [&](size_t bytes) -> void* {
        void* p = (void*)w;
        w += (bytes + 255) & ~(size_t)255;
        return p;
    };
    float* bufA    = (float*)alloc((size_t)N * HID * 4);   // fp8 g_a/g_b (+dummy rows) / bf16 g2 (decoder)
    int*   csr     = (int*)alloc(((size_t)E + 7 * (size_t)N + 8) * 4);  // padded CSR
    int*   row_ptr = (int*)alloc((size_t)(N + 1) * 4);
    int*   cnt     = (int*)alloc((size_t)N * 4);
    float* dinv    = (float*)alloc((size_t)N * 4);
    int*   partials= (int*)alloc(1024);
    float* emb     = (float*)alloc((size_t)NG * HID * 4);
    float* tbuf    = (float*)alloc((size_t)NG * HID * 4);
    int*   gcur    = (int*)alloc((size_t)NBIN * 16 * 4);
    int*   stage   = (int*)alloc((size_t)NBIN * SLOT * 4);  // 25.69 MB; reused as g3 (bf16)

    unsigned char* g_a = (unsigned char*)bufA;                            // 12.8 MB fp8 + dummy row
    unsigned char* g_b = (unsigned char*)bufA + ((size_t)N + 256) * HID;  // second slot (offset keeps alignment)
    unsigned short* g3 = (unsigned short*)stage;  // CSR staging dead after encoder

    const int NB = (N + 2047) / 2048;
    const int GB = 1024;  // gemm blocks (4 waves each)

    // CSR build: LDS-binned two-phase, padded rows (multiple of 8, dummy idx = N)
    zero_int_kernel<<<(NBIN * 16 + 255) / 256, 256, 0, stream>>>(gcur, NBIN * 16);
    bin1_kernel<<<(E + TILE - 1) / TILE, 256, 0, stream>>>(esrc, edst, gcur, stage, E, NBIN);
    bin_count_kernel<<<NBIN, 256, 0, stream>>>(gcur, stage, cnt, dinv, N);
    scan1_kernel<<<NB, 256, 0, stream>>>(cnt, row_ptr, partials, N);
    scan2_kernel<<<1, 128, 0, stream>>>(partials, NB);
    scan3_kernel<<<NB, 256, 0, stream>>>(row_ptr, partials, cnt, N);
    bin_fill_kernel<<<NBIN, 256, 0, stream>>>(gcur, stage, row_ptr, csr, N);
    pad_kernel<<<(N + 255) / 256, 256, 0, stream>>>(row_ptr, cnt, csr, N);
    zero_dummy_kernel<<<1, 128, 0, stream>>>((unsigned*)g_a, (unsigned*)g_b, N);

    // encoder: gemm1 -> g_a; {agg (fp8 h) + small fp8-A gemm} x2; fused final agg+pool -> emb
    zero_int_kernel<<<(NG * HID + 255) / 256, 256, 0, stream>>>((int*)emb, NG * HID);
    mfma_gemm<128, 64, 1, false, 0, 1, 2><<<GB, 256, 0, stream>>>(x, enc_W1, nullptr, dinv, nullptr,
                                                                  (float*)g_a, N);
    agg_f8_kernel<<<N / 32, 256, 0, stream>>>((const unsigned*)g_a, row_ptr, csr, dinv, enc_b1,
                                              (unsigned*)g_b, N, 1);
    mfma_gemm<64, 64, 1, false, 5, 1, 2><<<GB, 256, 0, stream>>>((const float*)g_b, enc_W2, nullptr,
                                                                 dinv, nullptr, (float*)g_a, N);
    agg_f8_kernel<<<N / 32, 256, 0, stream>>>((const unsigned*)g_a, row_ptr, csr, dinv, enc_b2,
                                              (unsigned*)g_b, N, 1);
    mfma_gemm<64, 64, 1, false, 5, 1, 2><<<GB, 256, 0, stream>>>((const float*)g_b, enc_W3, nullptr,
                                                                 dinv, nullptr, (float*)g_a, N);
    agg_pool_kernel<<<N / 32, 256, 0, stream>>>((const unsigned*)g_a, row_ptr, csr, dinv, enc_b3,
                                                emb, N);

    // decoder head
    decinit_kernel<<<(NG * 64 + 255) / 256, 256, 0, stream>>>(emb, dec_Wt, dec_bt, dec_W1, tbuf, NG);

    // decoder as 3 GEMMs with fused A-construction (bf16 intermediates):
    mfma_gemm<64, 64, 2, false, 2, 2, 1><<<GB, 256, 0, stream>>>(tbuf, dec_W2, nullptr, nullptr,
                                                                 dec_b1, bufA, N);
    mfma_gemm<64, 64, 2, false, 4, 2, 1><<<GB, 256, 0, stream>>>(bufA, dec_W3, nullptr, nullptr,
                                                                 dec_b2, (float*)g3, N);
    mfma_gemm<64, 128, 0, true, 4, 2, 0><<<GB, 256, 0, stream>>>((const float*)g3, out_W, out_b, nullptr,
                                                                 dec_b3, (float*)d_out, N);
}